// Round 13
// baseline (1259.459 us; speedup 1.0000x reference)
//
#include <hip/hip_runtime.h>

#define LEAKY(v) ((v) >= 0.f ? (v) : 0.2f*(v))

static const int B_ = 16;
static const int N_ = 1024;
static const int P_ = 16384;   // B*N
static const int KNN = 20;

typedef __attribute__((ext_vector_type(8))) short short8v;
typedef __attribute__((ext_vector_type(4))) float f32x4;

__device__ inline ushort f2bf(float f) {
    unsigned u = __float_as_uint(f);
    unsigned r = u + 0x7FFFu + ((u >> 16) & 1u);
    return (ushort)(r >> 16);
}
__device__ inline float bf2f(ushort h) {
    return __uint_as_float(((unsigned)h) << 16);
}

// ---------------- prep: W2 = [wA ; wB - wA] fp32 (layer-1 only) -------------
__global__ void prep_w2(const float* __restrict__ w, float* __restrict__ W2, int O, int C) {
    int i = blockIdx.x * 256 + threadIdx.x;
    int total = 2 * O * C;
    if (i < total) {
        int row = i / C, c = i % C;
        float val;
        if (row < O) val = w[row * 2 * C + c];
        else { int o = row - O; val = w[o * 2 * C + C + c] - w[o * 2 * C + c]; }
        W2[i] = val;
    }
}

// ---------------- prep W2 and split to bf16 [h|l|h] in one pass (L>=1) ------
__global__ void prep_w2_split(const float* __restrict__ w, ushort* __restrict__ WB2, int O, int C) {
    int i = blockIdx.x * 256 + threadIdx.x;
    int cpr = C >> 2;
    if (i >= 2 * O * cpr) return;
    int row = i / cpr, c4 = (i % cpr) * 4;
    float vv[4];
    #pragma unroll
    for (int j = 0; j < 4; j++) {
        int c = c4 + j;
        if (row < O) vv[j] = w[row * 2 * C + c];
        else { int o = row - O; vv[j] = w[o * 2 * C + C + c] - w[o * 2 * C + c]; }
    }
    ushort4 h, l;
    h.x = f2bf(vv[0]); l.x = f2bf(vv[0] - bf2f(h.x));
    h.y = f2bf(vv[1]); l.y = f2bf(vv[1] - bf2f(h.y));
    h.z = f2bf(vv[2]); l.z = f2bf(vv[2] - bf2f(h.z));
    h.w = f2bf(vv[3]); l.w = f2bf(vv[3] - bf2f(h.w));
    ushort* rowp = WB2 + (size_t)row * 3 * C + c4;
    *(ushort4*)(rowp)         = h;
    *(ushort4*)(rowp + C)     = l;
    *(ushort4*)(rowp + 2 * C) = h;
}

// ---------------- squared norms ----------------
__global__ void sqnorm(const float* __restrict__ x, int lda, int C, float* __restrict__ xx) {
    int p = blockIdx.x * 256 + threadIdx.x;
    if (p < P_) {
        const float* r = x + (size_t)p * lda;
        float s = 0.f;
        for (int c = 0; c < C; c++) s += r[c] * r[c];
        xx[p] = s;
    }
}

// ---------------- fp32 -> split-bf16 rows. mode0: [h|h|l], mode1: [h|l|h] ---
__global__ void conv_split(const float* __restrict__ src, int ld, int C, int rows,
                           ushort* __restrict__ dst, int mode) {
    int i = blockIdx.x * 256 + threadIdx.x;
    int cpr = C >> 2;
    if (i >= rows * cpr) return;
    int p = i / cpr, c4 = (i % cpr) * 4;
    float4 v = *(const float4*)(src + (size_t)p * ld + c4);
    ushort4 h, l;
    h.x = f2bf(v.x); l.x = f2bf(v.x - bf2f(h.x));
    h.y = f2bf(v.y); l.y = f2bf(v.y - bf2f(h.y));
    h.z = f2bf(v.z); l.z = f2bf(v.z - bf2f(h.z));
    h.w = f2bf(v.w); l.w = f2bf(v.w - bf2f(h.w));
    ushort* row = dst + (size_t)p * 3 * C + c4;
    if (mode == 0) {
        *(ushort4*)(row)         = h;
        *(ushort4*)(row + C)     = h;
        *(ushort4*)(row + 2 * C) = l;
    } else {
        *(ushort4*)(row)         = h;
        *(ushort4*)(row + C)     = l;
        *(ushort4*)(row + 2 * C) = h;
    }
}

// ---------------- FUSED dist + per-thread partial top-k ---------------------
// v2 of R10 with the three killers fixed (R10 post-mortem):
//  * staging uses the PROVEN k-major As[kk][r] slices (2-way free), not
//    column-major scatter (was 32-way conflicted);
//  * LDS 25.3KB (was 82KB -> 1 block/CU);
//  * ALL 256 threads select: thread (r=tid&63, q=tid>>6) owns a 16-col slice
//    per chunk, register-resident sorted top-20 via static shift-insert
//    (pattern proven register-promoted in R10: VGPR=132). Streams are
//    col-ascending -> lax.top_k tie order. 4 lists/row merged by topk_merge.
// GEMM is bit-identical to the passing dist_kernel (same staging, same
// `acc += a*w` order, same epilogue expression) -> same idx. fp32 mandatory
// (R3: bf16 dist flips near-tie neighbors).
template<int C>
__global__ __launch_bounds__(256)
void dist_topk_fused(const float* __restrict__ x, int lda,
                     const float* __restrict__ xx,
                     float* __restrict__ lv, int* __restrict__ lc) {
    __shared__ float As[16][68];
    __shared__ float Bs[16][68];
    __shared__ float dt[64 * 65];
    int b = blockIdx.y;
    int brow = blockIdx.x * 64;
    const float* xb = x + (size_t)b * N_ * lda;
    const float* xxb = xx + b * N_;
    int tid = threadIdx.x;
    int tx = tid & 15, ty = tid >> 4;
    int r = tid & 63, q = tid >> 6;

    float xxn = xxb[brow + r];
    float t20v[20]; int t20c[20];
    #pragma unroll
    for (int j = 0; j < 20; j++) { t20v[j] = -3.4e38f; t20c[j] = 0; }

    for (int ch = 0; ch < 16; ch++) {
        int cb = ch * 64;
        float acc[4][4] = {};
        for (int k0 = 0; k0 < C; k0 += 16) {
            __syncthreads();   // protects As/Bs and (first iter) prev-chunk dt readers
            for (int l = tid; l < 1024; l += 256) {
                int r2 = l >> 4, kk = l & 15, kg = k0 + kk;
                As[kk][r2] = (kg < C) ? xb[(size_t)(brow + r2) * lda + kg] : 0.f;
                Bs[kk][r2] = (kg < C) ? xb[(size_t)(cb + r2) * lda + kg] : 0.f;
            }
            __syncthreads();
            #pragma unroll
            for (int kk = 0; kk < 16; kk++) {
                float4 a4 = *(const float4*)&As[kk][ty * 4];
                float4 w4 = *(const float4*)&Bs[kk][tx * 4];
                float a[4] = {a4.x, a4.y, a4.z, a4.w};
                float w[4] = {w4.x, w4.y, w4.z, w4.w};
                #pragma unroll
                for (int i = 0; i < 4; i++)
                    #pragma unroll
                    for (int j = 0; j < 4; j++) acc[i][j] += a[i] * w[j];
            }
        }
        #pragma unroll
        for (int i = 0; i < 4; i++)
            #pragma unroll
            for (int j = 0; j < 4; j++)
                dt[(ty * 4 + i) * 65 + tx * 4 + j] = acc[i][j];
        __syncthreads();

        // selection: thread (r, q) scans cols cb+q*16 .. +15 of row r
        float4 xq0 = *(const float4*)&xxb[cb + q * 16];
        float4 xq1 = *(const float4*)&xxb[cb + q * 16 + 4];
        float4 xq2 = *(const float4*)&xxb[cb + q * 16 + 8];
        float4 xq3 = *(const float4*)&xxb[cb + q * 16 + 12];
        float xq[16] = {xq0.x, xq0.y, xq0.z, xq0.w, xq1.x, xq1.y, xq1.z, xq1.w,
                        xq2.x, xq2.y, xq2.z, xq2.w, xq3.x, xq3.y, xq3.z, xq3.w};
        #pragma unroll
        for (int j = 0; j < 16; j++) {
            float a = dt[r * 65 + q * 16 + j];
            float v = 2.f * a - xxn - xq[j];
            if (v > t20v[19]) {
                int col = cb + q * 16 + j;
                #pragma unroll
                for (int jj = 19; jj >= 1; --jj) {
                    bool sh  = v > t20v[jj - 1];
                    bool in_ = !sh && (v > t20v[jj]);
                    t20v[jj] = sh ? t20v[jj - 1] : (in_ ? v : t20v[jj]);
                    t20c[jj] = sh ? t20c[jj - 1] : (in_ ? col : t20c[jj]);
                }
                bool i0 = v > t20v[0];
                t20v[0] = i0 ? v : t20v[0];
                t20c[0] = i0 ? col : t20c[0];
            }
        }
    }
    // write the 4 per-row lists, i-major-last for coalesced merge reads
    size_t p = (size_t)b * N_ + brow + r;
    #pragma unroll
    for (int i = 0; i < 20; i++) {
        lv[(size_t)(q * 20 + i) * P_ + p] = t20v[i];
        lc[(size_t)(q * 20 + i) * P_ + p] = t20c[i];
    }
}

// ---------------- merge 4 sorted top-20 lists -> final top-20 ---------------
// Named scalars only (no runtime-indexed register arrays — rule #20).
__global__ void topk_merge(const float* __restrict__ lv, const int* __restrict__ lc,
                           int* __restrict__ idx) {
    int p = blockIdx.x * 256 + threadIdx.x;
    if (p >= P_) return;
    const float* Lv = lv + p;
    const int*   Lc = lc + p;
    float hv0 = Lv[0], hv1 = Lv[20 * P_], hv2 = Lv[40 * P_], hv3 = Lv[60 * P_];
    int   hc0 = Lc[0], hc1 = Lc[20 * P_], hc2 = Lc[40 * P_], hc3 = Lc[60 * P_];
    int n0 = 1, n1 = 1, n2 = 1, n3 = 1;
    int* out = idx + (size_t)p * KNN;
    #pragma unroll 1
    for (int it = 0; it < KNN; it++) {
        float bv = hv0; int bc = hc0; int bq = 0;
        if (hv1 > bv || (hv1 == bv && hc1 < bc)) { bv = hv1; bc = hc1; bq = 1; }
        if (hv2 > bv || (hv2 == bv && hc2 < bc)) { bv = hv2; bc = hc2; bq = 2; }
        if (hv3 > bv || (hv3 == bv && hc3 < bc)) { bv = hv3; bc = hc3; bq = 3; }
        out[it] = bc;
        if (bq == 0) {
            hv0 = (n0 < 20) ? Lv[(size_t)n0 * P_] : -3.4e38f;
            hc0 = (n0 < 20) ? Lc[(size_t)n0 * P_] : 0;
            n0++;
        } else if (bq == 1) {
            hv1 = (n1 < 20) ? Lv[(size_t)(20 + n1) * P_] : -3.4e38f;
            hc1 = (n1 < 20) ? Lc[(size_t)(20 + n1) * P_] : 0;
            n1++;
        } else if (bq == 2) {
            hv2 = (n2 < 20) ? Lv[(size_t)(40 + n2) * P_] : -3.4e38f;
            hc2 = (n2 < 20) ? Lc[(size_t)(40 + n2) * P_] : 0;
            n2++;
        } else {
            hv3 = (n3 < 20) ? Lv[(size_t)(60 + n3) * P_] : -3.4e38f;
            hc3 = (n3 < 20) ? Lc[(size_t)(60 + n3) * P_] : 0;
            n3++;
        }
    }
}

// ---------------- fp32 GEMM (layer-1 uv only, K=3) --------------------------
__global__ void gemm_wt(const float* __restrict__ A, int lda,
                        const float* __restrict__ W, int ldw,
                        float* __restrict__ out, int ldo, int K) {
    __shared__ float As[16][68];
    __shared__ float Ws[16][68];
    int m0 = blockIdx.y * 64, n0 = blockIdx.x * 64;
    int tid = threadIdx.x;
    int tx = tid & 15, ty = tid >> 4;
    float acc[4][4] = {};
    for (int k0 = 0; k0 < K; k0 += 16) {
        for (int l = tid; l < 1024; l += 256) {
            int r = l >> 4, kk = l & 15, kg = k0 + kk;
            As[kk][r] = (kg < K) ? A[(size_t)(m0 + r) * lda + kg] : 0.f;
            Ws[kk][r] = (kg < K) ? W[(size_t)(n0 + r) * ldw + kg] : 0.f;
        }
        __syncthreads();
        #pragma unroll
        for (int kk = 0; kk < 16; kk++) {
            float4 a4 = *(const float4*)&As[kk][ty * 4];
            float4 w4 = *(const float4*)&Ws[kk][tx * 4];
            float a[4] = {a4.x, a4.y, a4.z, a4.w};
            float w[4] = {w4.x, w4.y, w4.z, w4.w};
            #pragma unroll
            for (int i = 0; i < 4; i++)
                #pragma unroll
                for (int j = 0; j < 4; j++) acc[i][j] += a[i] * w[j];
        }
        __syncthreads();
    }
    for (int i = 0; i < 4; i++) {
        int m = m0 + ty * 4 + i;
        for (int j = 0; j < 4; j++) {
            int n = n0 + tx * 4 + j;
            out[(size_t)m * ldo + n] = acc[i][j];
        }
    }
}

// ---------------- unified split-bf16 MFMA GEMM ------------------------------
// MODE 0: uv; MODE 2: final conv + fused transposed col stats.
// Bijective XCD swizzle (R12): each XCD owns a contiguous y-band.
template<int MODE>
__global__ __launch_bounds__(256, 2)
void gemm_mfma(const ushort* __restrict__ A, const ushort* __restrict__ Bw,
               int K, int nkt, float* __restrict__ out, int ldo,
               float* __restrict__ part) {
    __shared__ ushort lA[128 * 64];
    __shared__ ushort lB[128 * 64];
    int tid = threadIdx.x;
    int lane = tid & 63;
    int wid = tid >> 6;
    int wr = wid >> 1, wc = wid & 1;

    int nx = gridDim.x;
    int ypb = gridDim.y >> 3;
    int bid = blockIdx.y * nx + blockIdx.x;
    int xcd = bid & 7, pos = bid >> 3;
    int yy = xcd * ypb + pos / nx;
    int xx2 = pos % nx;
    int m0 = yy * 128, n0 = xx2 * 128;

    const ushort* pA = A + (size_t)m0 * K;
    const ushort* pB = Bw + (size_t)n0 * K;
    int rowu = tid >> 3, kcu = (tid & 7) * 8;

    f32x4 acc[4][4] = {};
    short8v ra[4], rb[4];
    #pragma unroll
    for (int j = 0; j < 4; j++) {
        int row = rowu + j * 32;
        ra[j] = *(const short8v*)(pA + (size_t)row * K + kcu);
        rb[j] = *(const short8v*)(pB + (size_t)row * K + kcu);
    }

    for (int kt = 0; kt < nkt; kt++) {
        __syncthreads();
        #pragma unroll
        for (int j = 0; j < 4; j++) {
            int row = rowu + j * 32;
            int off = (row * 128 + kcu * 2) ^ ((row & 7) << 4);
            *(short8v*)((char*)lA + off) = ra[j];
            *(short8v*)((char*)lB + off) = rb[j];
        }
        __syncthreads();
        if (kt < nkt - 1) {
            int kbase = (kt + 1) * 64 + kcu;
            #pragma unroll
            for (int j = 0; j < 4; j++) {
                int row = rowu + j * 32;
                ra[j] = *(const short8v*)(pA + (size_t)row * K + kbase);
                rb[j] = *(const short8v*)(pB + (size_t)row * K + kbase);
            }
        }
        #pragma unroll
        for (int ks = 0; ks < 2; ks++) {
            short8v af[4], bg[4];
            int kb2 = (ks * 32 + ((lane >> 4) << 3)) * 2;
            #pragma unroll
            for (int mb = 0; mb < 4; mb++) {
                int row = wr * 64 + mb * 16 + (lane & 15);
                int off = (row * 128 + kb2) ^ ((row & 7) << 4);
                af[mb] = *(const short8v*)((const char*)lA + off);
            }
            #pragma unroll
            for (int nb = 0; nb < 4; nb++) {
                int row = wc * 64 + nb * 16 + (lane & 15);
                int off = (row * 128 + kb2) ^ ((row & 7) << 4);
                bg[nb] = *(const short8v*)((const char*)lB + off);
            }
            #pragma unroll
            for (int mb = 0; mb < 4; mb++)
                #pragma unroll
                for (int nb = 0; nb < 4; nb++)
                    acc[mb][nb] = __builtin_amdgcn_mfma_f32_16x16x32_bf16(af[mb], bg[nb], acc[mb][nb], 0, 0, 0);
        }
    }

    int rbase = m0 + wr * 64 + ((lane >> 4) << 2);
    int cbase = n0 + wc * 64 + (lane & 15);

    if (MODE == 0) {
        #pragma unroll
        for (int mb = 0; mb < 4; mb++)
            #pragma unroll
            for (int nb = 0; nb < 4; nb++)
                #pragma unroll
                for (int r = 0; r < 4; r++)
                    out[(size_t)(rbase + mb * 16 + r) * ldo + cbase + nb * 16] = acc[mb][nb][r];
    } else {
        float* smS = (float*)lA;
        float* smQ = (float*)lB;
        __syncthreads();
        #pragma unroll
        for (int nb = 0; nb < 4; nb++) {
            float s = 0.f, q = 0.f;
            #pragma unroll
            for (int mb = 0; mb < 4; mb++)
                #pragma unroll
                for (int r = 0; r < 4; r++) {
                    float v = acc[mb][nb][r];
                    out[(size_t)(rbase + mb * 16 + r) * ldo + cbase + nb * 16] = v;
                    s += v; q += v * v;
                }
            s += __shfl_xor(s, 16, 64); s += __shfl_xor(s, 32, 64);
            q += __shfl_xor(q, 16, 64); q += __shfl_xor(q, 32, 64);
            if ((lane >> 4) == 0) {
                smS[wid * 64 + nb * 16 + lane] = s;
                smQ[wid * 64 + nb * 16 + lane] = q;
            }
        }
        __syncthreads();
        if (tid < 128) {
            int wcs = tid >> 6, c = tid & 63;
            float s = smS[wcs * 64 + c] + smS[(2 + wcs) * 64 + c];
            float q = smQ[wcs * 64 + c] + smQ[(2 + wcs) * 64 + c];
            int col = n0 + wcs * 64 + c;
            part[(size_t)col * 128 + yy] = s;
            part[131072 + (size_t)col * 128 + yy] = q;
        }
    }
}

// ---------------- gather neighbors, per-(p,o) max/min, per-channel stats ----
__global__ void gather_stats(const float* __restrict__ uv, const int* __restrict__ idx, int O,
                             float* __restrict__ ymax, float* __restrict__ ymin,
                             double* __restrict__ part, int ppb) {
    __shared__ double sd[256], sd2[256];
    int t = threadIdx.x;
    int R = 256 / O;
    int o = t % O;
    int q = t / O;
    double s = 0.0, s2 = 0.0;
    int p0 = blockIdx.x * ppb;
    int ld = 2 * O;
    for (int lp = q; lp < ppb; lp += R) {
        int p = p0 + lp;
        int b = p >> 10;
        const int* ir = idx + (size_t)p * KNN;
        float v = uv[(size_t)p * ld + O + o];
        float mx = -3.4e38f, mn = 3.4e38f;
        for (int kk = 0; kk < KNN; kk++) {
            int j = ir[kk];
            float u = uv[((size_t)((b << 10) + j)) * ld + o];
            float y = u + v;
            mx = fmaxf(mx, y); mn = fminf(mn, y);
            s += (double)y; s2 += (double)y * (double)y;
        }
        ymax[(size_t)p * O + o] = mx;
        ymin[(size_t)p * O + o] = mn;
    }
    sd[t] = s; sd2[t] = s2;
    __syncthreads();
    if (t < O) {
        double a = 0.0, a2 = 0.0;
        for (int qq = 0; qq < R; qq++) { a += sd[qq * O + t]; a2 += sd2[qq * O + t]; }
        part[(size_t)t * 1024 + blockIdx.x] = a;
        part[(size_t)(O + t) * 1024 + blockIdx.x] = a2;
    }
}

// ---------------- parallel finalize: one block per channel ------------------
__global__ void finalize_t(const double* __restrict__ part, int O,
                           const float* __restrict__ g, const float* __restrict__ bt,
                           float* __restrict__ scale, float* __restrict__ shift, double invCount) {
    __shared__ double sa[4], sb[4];
    int o = blockIdx.x;
    int t = threadIdx.x;
    int lane = t & 63, w = t >> 6;
    const double* ps = part + (size_t)o * 1024;
    const double* pq = part + (size_t)(O + o) * 1024;
    double s = 0.0, s2 = 0.0;
    #pragma unroll
    for (int b = 0; b < 4; b++) { s += ps[t + b * 256]; s2 += pq[t + b * 256]; }
    #pragma unroll
    for (int off = 32; off > 0; off >>= 1) { s += __shfl_xor(s, off, 64); s2 += __shfl_xor(s2, off, 64); }
    if (lane == 0) { sa[w] = s; sb[w] = s2; }
    __syncthreads();
    if (t == 0) {
        s = sa[0] + sa[1] + sa[2] + sa[3];
        s2 = sb[0] + sb[1] + sb[2] + sb[3];
        double mean = s * invCount;
        double var = s2 * invCount - mean * mean;
        if (var < 0.0) var = 0.0;
        float sc = (float)(1.0 / sqrt(var + 1e-5)) * g[o];
        scale[o] = sc;
        shift[o] = bt[o] - (float)mean * sc;
    }
}

// ---------------- parallel finalize for float partials (final conv) ---------
__global__ void finalize_f_t(const float* __restrict__ part,
                             const float* __restrict__ g, const float* __restrict__ bt,
                             float* __restrict__ scale, float* __restrict__ shift, double invCount) {
    __shared__ double sa[2], sb[2];
    int o = blockIdx.x;
    int t = threadIdx.x;   // 128 threads
    int lane = t & 63, w = t >> 6;
    double s  = (double)part[(size_t)o * 128 + t];
    double s2 = (double)part[131072 + (size_t)o * 128 + t];
    #pragma unroll
    for (int off = 32; off > 0; off >>= 1) { s += __shfl_xor(s, off, 64); s2 += __shfl_xor(s2, off, 64); }
    if (lane == 0) { sa[w] = s; sb[w] = s2; }
    __syncthreads();
    if (t == 0) {
        s = sa[0] + sa[1];
        s2 = sb[0] + sb[1];
        double mean = s * invCount;
        double var = s2 * invCount - mean * mean;
        if (var < 0.0) var = 0.0;
        float sc = (float)(1.0 / sqrt(var + 1e-5)) * g[o];
        scale[o] = sc;
        shift[o] = bt[o] - (float)mean * sc;
    }
}

// ---------------- edge conv epilogue: BN + leaky (max over k done) ----------
__global__ void apply_edge(const float* __restrict__ ymax, const float* __restrict__ ymin,
                           const float* __restrict__ scale, const float* __restrict__ shift,
                           float* __restrict__ xcat, int O, int off) {
    int i = blockIdx.x * 256 + threadIdx.x;
    if (i < P_ * O) {
        int p = i / O, o = i % O;
        float sc = scale[o];
        float y = (sc >= 0.f) ? ymax[i] : ymin[i];
        float val = y * sc + shift[o];
        xcat[(size_t)p * 512 + off + o] = LEAKY(val);
    }
}

// ---------------- global max+mean pool with fused BN+leaky ------------------
__global__ void pool_kernel(const float* __restrict__ h, const float* __restrict__ scale,
                            const float* __restrict__ shift, float* __restrict__ pooled) {
    __shared__ float smax[256];
    __shared__ double ssum[256];
    int b = blockIdx.x, og = blockIdx.y;
    int t = threadIdx.x;
    int o = og * 64 + (t & 63);
    int ch = t >> 6;
    float sc = scale[o], sh = shift[o];
    float mx = -3.4e38f;
    double sm = 0.0;
    for (int n = ch * 256; n < ch * 256 + 256; n++) {
        float y = h[((size_t)b * N_ + n) * 1024 + o] * sc + sh;
        y = LEAKY(y);
        mx = fmaxf(mx, y);
        sm += (double)y;
    }
    smax[t] = mx; ssum[t] = sm;
    __syncthreads();
    if (t < 64) {
        for (int c = 1; c < 4; c++) { mx = fmaxf(mx, smax[c * 64 + t]); sm += ssum[c * 64 + t]; }
        pooled[(size_t)b * 2048 + o] = mx;
        pooled[(size_t)b * 2048 + 1024 + o] = (float)(sm * (1.0 / N_));
    }
}

// ---------------- small FC: one wave per output -----------------------------
__global__ void fc_kernel(const float* __restrict__ in, int ldi,
                          const float* __restrict__ w, int ldw,
                          const float* __restrict__ bias,
                          float* __restrict__ out, int M, int Nn, int K) {
    int gw = (blockIdx.x * 256 + threadIdx.x) >> 6;
    int lane = threadIdx.x & 63;
    if (gw >= M * Nn) return;
    int m = gw / Nn, n = gw % Nn;
    const float* a = in + (size_t)m * ldi;
    const float* ww = w + (size_t)n * ldw;
    float s = 0.f;
    for (int kk = lane; kk < K; kk += 64) s += a[kk] * ww[kk];
    #pragma unroll
    for (int off = 32; off > 0; off >>= 1) s += __shfl_xor(s, off, 64);
    if (lane == 0) out[(size_t)m * Nn + n] = s + bias[n];
}

// ---------------- BN over batch axis (M=16) + leaky, in place ---------------
__global__ void bn_rows(float* __restrict__ z, int M, int O,
                        const float* __restrict__ g, const float* __restrict__ bt) {
    int o = blockIdx.x * 256 + threadIdx.x;
    if (o >= O) return;
    double s = 0.0, s2 = 0.0;
    for (int m = 0; m < M; m++) {
        float y = z[(size_t)m * O + o];
        s += (double)y; s2 += (double)y * (double)y;
    }
    double mean = s / M;
    double var = s2 / M - mean * mean;
    if (var < 0.0) var = 0.0;
    float sc = (float)(1.0 / sqrt(var + 1e-5)) * g[o];
    float sh = bt[o] - (float)mean * sc;
    for (int m = 0; m < M; m++) {
        float y = z[(size_t)m * O + o] * sc + sh;
        z[(size_t)m * O + o] = LEAKY(y);
    }
}

extern "C" void kernel_launch(void* const* d_in, const int* in_sizes, int n_in,
                              void* d_out, int out_size, void* d_ws, size_t ws_size,
                              hipStream_t stream) {
    const float* cloud = (const float*)d_in[0];
    const float* wf  = (const float*)d_in[17];
    const float* gf  = (const float*)d_in[19];
    const float* btf = (const float*)d_in[20];
    const float* wl1 = (const float*)d_in[21];
    const float* bl1 = (const float*)d_in[22];
    const float* gl1 = (const float*)d_in[23];
    const float* btl1= (const float*)d_in[24];
    const float* wl2 = (const float*)d_in[25];
    const float* bl2 = (const float*)d_in[26];
    const float* gl2 = (const float*)d_in[27];
    const float* btl2= (const float*)d_in[28];
    const float* wl3 = (const float*)d_in[29];
    const float* bl3 = (const float*)d_in[30];

    // workspace layout (bytes)
    const size_t OFF_XCAT  = 0;                        // 33554432
    const size_t OFF_UV    = 33554432;                 // 33554432 (A2 aliases UV+YMAX)
    const size_t OFF_YMAX  = 67108864;                 // 16777216 (xA alias: 12.6MB max)
    const size_t OFF_YMIN  = 83886080;                 // 16777216 (B2 alias)
    const size_t OFF_DIST  = 100663296;                // 67108864: lv/lc during layers (10.5MB), hraw at end
    const size_t OFF_IDX   = 167772160;                // 1310720
    const size_t OFF_XX    = 169082880;                // 65536
    const size_t OFF_W2    = 169148416;                // 524288
    const size_t OFF_PART  = 169676800;                // 4194304: part doubles (WB2 aliases head)
    const size_t OFF_SCALE = 173871104;                // 4096
    const size_t OFF_SHIFT = 173875200;                // 4096
    const size_t OFF_POOL  = 173879296;                // 131072
    const size_t OFF_Z1    = 174010368;                // 32768
    const size_t OFF_Z2    = 174043136;                // 16384
    const size_t TOTAL     = 174059520;
    if (ws_size < TOTAL) return;

    char* ws = (char*)d_ws;
    float* xcat  = (float*)(ws + OFF_XCAT);
    float* uv    = (float*)(ws + OFF_UV);
    float* ymax  = (float*)(ws + OFF_YMAX);
    float* ymin  = (float*)(ws + OFF_YMIN);
    float* hraw  = (float*)(ws + OFF_DIST);
    float* lv    = (float*)(ws + OFF_DIST);            // 4*20*P_*4 = 5242880
    int*   lc    = (int*)  (ws + OFF_DIST + 5242880);  // 5242880
    ushort* A2   = (ushort*)(ws + OFF_UV);
    ushort* B2   = (ushort*)(ws + OFF_YMIN);
    ushort* xA   = (ushort*)(ws + OFF_YMAX);
    ushort* WB2  = (ushort*)(ws + OFF_PART);
    int*   idx   = (int*)  (ws + OFF_IDX);
    float* xx    = (float*)(ws + OFF_XX);
    float* W2    = (float*)(ws + OFF_W2);
    double* part = (double*)(ws + OFF_PART);
    float* partf = (float*)(ws + OFF_PART);
    float* scale = (float*)(ws + OFF_SCALE);
    float* shift = (float*)(ws + OFF_SHIFT);
    float* pooled= (float*)(ws + OFF_POOL);
    float* z1    = (float*)(ws + OFF_Z1);
    float* z2    = (float*)(ws + OFF_Z2);

    const int Cs[4]   = {3, 64, 64, 128};
    const int Os[4]   = {64, 64, 128, 256};
    const int offs[4] = {0, 64, 128, 256};

    for (int L = 0; L < 4; L++) {
        int C = Cs[L], O = Os[L];
        const float* w  = (const float*)d_in[1 + 4 * L];
        const float* g  = (const float*)d_in[3 + 4 * L];
        const float* bt = (const float*)d_in[4 + 4 * L];
        const float* x  = (L == 0) ? cloud : (xcat + offs[L - 1]);
        int lda = (L == 0) ? 3 : 512;

        sqnorm<<<(P_ + 255) / 256, 256, 0, stream>>>(x, lda, C, xx);
        if (C == 3)
            dist_topk_fused<3><<<dim3(16, 16), 256, 0, stream>>>(x, lda, xx, lv, lc);
        else if (C == 64)
            dist_topk_fused<64><<<dim3(16, 16), 256, 0, stream>>>(x, lda, xx, lv, lc);
        else
            dist_topk_fused<128><<<dim3(16, 16), 256, 0, stream>>>(x, lda, xx, lv, lc);
        topk_merge<<<P_ / 256, 256, 0, stream>>>(lv, lc, idx);

        if (L == 0) {
            prep_w2<<<(2 * O * C + 255) / 256, 256, 0, stream>>>(w, W2, O, C);
            gemm_wt<<<dim3(2 * O / 64, P_ / 64), 256, 0, stream>>>(x, lda, W2, C, uv, 2 * O, C);
        } else {
            int K3 = 3 * C, nkt = K3 / 64;
            conv_split<<<(P_ * (C / 4) + 255) / 256, 256, 0, stream>>>(x, lda, C, P_, xA, 0);
            prep_w2_split<<<(2 * O * (C / 4) + 255) / 256, 256, 0, stream>>>(w, WB2, O, C);
            gemm_mfma<0><<<dim3(2 * O / 128, 128), 256, 0, stream>>>(xA, WB2, K3, nkt, uv, 2 * O, nullptr);
        }

        gather_stats<<<1024, 256, 0, stream>>>(uv, idx, O, ymax, ymin, part, 16);
        finalize_t<<<O, 256, 0, stream>>>(part, O, g, bt, scale, shift, 1.0 / ((double)P_ * KNN));
        apply_edge<<<(P_ * O + 255) / 256, 256, 0, stream>>>(ymax, ymin, scale, shift, xcat, O, offs[L]);
    }

    // final 1x1 conv via split-bf16 MFMA GEMM with fused (transposed) col stats
    conv_split<<<(P_ * 128 + 255) / 256, 256, 0, stream>>>(xcat, 512, 512, P_, A2, 0);
    conv_split<<<(1024 * 128 + 255) / 256, 256, 0, stream>>>(wf, 512, 512, 1024, B2, 1);
    gemm_mfma<2><<<dim3(8, 128), 256, 0, stream>>>(A2, B2, 1536, 24, hraw, 1024, partf);

    finalize_f_t<<<1024, 128, 0, stream>>>(partf, gf, btf, scale, shift, 1.0 / (double)P_);
    pool_kernel<<<dim3(16, 16), 256, 0, stream>>>(hraw, scale, shift, pooled);

    // MLP head
    fc_kernel<<<(16 * 512 * 64) / 256, 256, 0, stream>>>(pooled, 2048, wl1, 2048, bl1, z1, 16, 512, 2048);
    bn_rows<<<2, 256, 0, stream>>>(z1, 16, 512, gl1, btl1);
    fc_kernel<<<(16 * 256 * 64) / 256, 256, 0, stream>>>(z1, 512, wl2, 512, bl2, z2, 16, 256, 512);
    bn_rows<<<1, 256, 0, stream>>>(z2, 16, 256, gl2, btl2);
    fc_kernel<<<(16 * 40 * 64 + 255) / 256, 256, 0, stream>>>(z2, 256, wl3, 256, bl3, (float*)d_out, 16, 40, 256);
}

// Round 15
// 940.670 us; speedup vs baseline: 1.3389x; 1.3389x over previous
//
#include <hip/hip_runtime.h>

#define LEAKY(v) ((v) >= 0.f ? (v) : 0.2f*(v))

static const int B_ = 16;
static const int N_ = 1024;
static const int P_ = 16384;   // B*N
static const int KNN = 20;

typedef __attribute__((ext_vector_type(8))) short short8v;
typedef __attribute__((ext_vector_type(4))) float f32x4;

__device__ inline ushort f2bf(float f) {
    unsigned u = __float_as_uint(f);
    unsigned r = u + 0x7FFFu + ((u >> 16) & 1u);
    return (ushort)(r >> 16);
}
__device__ inline float bf2f(ushort h) {
    return __uint_as_float(((unsigned)h) << 16);
}

// ---------------- prep: W2 = [wA ; wB - wA] fp32 (layer-1 only) -------------
__global__ void prep_w2(const float* __restrict__ w, float* __restrict__ W2, int O, int C) {
    int i = blockIdx.x * 256 + threadIdx.x;
    int total = 2 * O * C;
    if (i < total) {
        int row = i / C, c = i % C;
        float val;
        if (row < O) val = w[row * 2 * C + c];
        else { int o = row - O; val = w[o * 2 * C + C + c] - w[o * 2 * C + c]; }
        W2[i] = val;
    }
}

// ---------------- prep W2 and split to bf16 [h|l|h] in one pass (L>=1) ------
__global__ void prep_w2_split(const float* __restrict__ w, ushort* __restrict__ WB2, int O, int C) {
    int i = blockIdx.x * 256 + threadIdx.x;
    int cpr = C >> 2;
    if (i >= 2 * O * cpr) return;
    int row = i / cpr, c4 = (i % cpr) * 4;
    float vv[4];
    #pragma unroll
    for (int j = 0; j < 4; j++) {
        int c = c4 + j;
        if (row < O) vv[j] = w[row * 2 * C + c];
        else { int o = row - O; vv[j] = w[o * 2 * C + C + c] - w[o * 2 * C + c]; }
    }
    ushort4 h, l;
    h.x = f2bf(vv[0]); l.x = f2bf(vv[0] - bf2f(h.x));
    h.y = f2bf(vv[1]); l.y = f2bf(vv[1] - bf2f(h.y));
    h.z = f2bf(vv[2]); l.z = f2bf(vv[2] - bf2f(h.z));
    h.w = f2bf(vv[3]); l.w = f2bf(vv[3] - bf2f(h.w));
    ushort* rowp = WB2 + (size_t)row * 3 * C + c4;
    *(ushort4*)(rowp)         = h;
    *(ushort4*)(rowp + C)     = l;
    *(ushort4*)(rowp + 2 * C) = h;
}

// ---------------- squared norms ----------------
__global__ void sqnorm(const float* __restrict__ x, int lda, int C, float* __restrict__ xx) {
    int p = blockIdx.x * 256 + threadIdx.x;
    if (p < P_) {
        const float* r = x + (size_t)p * lda;
        float s = 0.f;
        for (int c = 0; c < C; c++) s += r[c] * r[c];
        xx[p] = s;
    }
}

// ---------------- fp32 -> split-bf16 rows. mode0: [h|h|l], mode1: [h|l|h] ---
__global__ void conv_split(const float* __restrict__ src, int ld, int C, int rows,
                           ushort* __restrict__ dst, int mode) {
    int i = blockIdx.x * 256 + threadIdx.x;
    int cpr = C >> 2;
    if (i >= rows * cpr) return;
    int p = i / cpr, c4 = (i % cpr) * 4;
    float4 v = *(const float4*)(src + (size_t)p * ld + c4);
    ushort4 h, l;
    h.x = f2bf(v.x); l.x = f2bf(v.x - bf2f(h.x));
    h.y = f2bf(v.y); l.y = f2bf(v.y - bf2f(h.y));
    h.z = f2bf(v.z); l.z = f2bf(v.z - bf2f(h.z));
    h.w = f2bf(v.w); l.w = f2bf(v.w - bf2f(h.w));
    ushort* row = dst + (size_t)p * 3 * C + c4;
    if (mode == 0) {
        *(ushort4*)(row)         = h;
        *(ushort4*)(row + C)     = h;
        *(ushort4*)(row + 2 * C) = l;
    } else {
        *(ushort4*)(row)         = h;
        *(ushort4*)(row + C)     = l;
        *(ushort4*)(row + 2 * C) = h;
    }
}

// ---------------- FUSED dist + partial top-k, v3 (R14 OOB fixed) ------------
// R14 bug: C<16 staging loop bound was 2048 -> r2 up to 127, OOB writes past
// As[16][68] stomping Bs/dt (layer-1 kNN garbage). Proven bound is 1024.
// v3 structure: grid (16 panels, 4 col-groups, 16 batches) = 1024 blocks for
// TLP (R13 had 256 = 1/CU, latency-bound). Block sweeps 4 chunks of 64 cols;
// per-row the 4 q-slice lists merge IN-BLOCK (LDS tournament) to one top-20
// per (row,group); global topk_merge merges groups. GEMM staging/order/
// epilogue bit-identical to the proven dist_kernel -> identical idx.
// fp32 mandatory (R3: bf16 dist flips near-tie kNN).
template<int C>
__global__ __launch_bounds__(256)
void dist_topk_fused(const float* __restrict__ x, int lda,
                     const float* __restrict__ xx,
                     float* __restrict__ lv, int* __restrict__ lc) {
    __shared__ char smem[30720];
    float (*As)[68] = (float(*)[68])smem;            // 16x68 f = 4352B
    float (*Bs)[68] = (float(*)[68])(smem + 4352);   // 4352B
    float* dt  = (float*)(smem + 8704);              // 64*65 f = 16640B (ends 25344)
    float*  Mv = (float*)smem;                       // lists alias: 80*64 f = 20480B
    ushort* Mc = (ushort*)(smem + 20480);            // 80*64 us = 10240B (ends 30720)

    int panel = blockIdx.x, cg = blockIdx.y, b = blockIdx.z;
    int brow = panel * 64;
    const float* xb = x + (size_t)b * N_ * lda;
    const float* xxb = xx + b * N_;
    int tid = threadIdx.x;
    int tx = tid & 15, ty = tid >> 4;
    int r = tid & 63, q = tid >> 6;

    float xxn = xxb[brow + r];
    float t20v[20]; int t20c[20];
    #pragma unroll
    for (int j = 0; j < 20; j++) { t20v[j] = -3.4e38f; t20c[j] = 0; }

    for (int ch = 0; ch < 4; ch++) {
        int cb = (cg * 4 + ch) * 64;
        float acc[4][4] = {};
        for (int k0 = 0; k0 < C; k0 += 16) {
            __syncthreads();   // protects As/Bs and prev-chunk dt readers
            if (C >= 16) {
                #pragma unroll
                for (int l = tid; l < 512; l += 256) {
                    int isB = l >> 8;
                    int rr = (l & 255) >> 2;
                    int qq = l & 3;
                    int base = isB ? cb : brow;
                    float4 v4 = *(const float4*)&xb[(size_t)(base + rr) * lda + k0 + qq * 4];
                    float (*S)[68] = isB ? Bs : As;
                    S[qq * 4 + 0][rr] = v4.x; S[qq * 4 + 1][rr] = v4.y;
                    S[qq * 4 + 2][rr] = v4.z; S[qq * 4 + 3][rr] = v4.w;
                }
            } else {
                for (int l = tid; l < 1024; l += 256) {   // 1024! (R14 had 2048 = OOB)
                    int r2 = l >> 4, kk = l & 15, kg = k0 + kk;
                    As[kk][r2] = (kg < C) ? xb[(size_t)(brow + r2) * lda + kg] : 0.f;
                    Bs[kk][r2] = (kg < C) ? xb[(size_t)(cb + r2) * lda + kg] : 0.f;
                }
            }
            __syncthreads();
            #pragma unroll
            for (int kk = 0; kk < 16; kk++) {
                float4 a4 = *(const float4*)&As[kk][ty * 4];
                float4 w4 = *(const float4*)&Bs[kk][tx * 4];
                float a[4] = {a4.x, a4.y, a4.z, a4.w};
                float w[4] = {w4.x, w4.y, w4.z, w4.w};
                #pragma unroll
                for (int i = 0; i < 4; i++)
                    #pragma unroll
                    for (int j = 0; j < 4; j++) acc[i][j] += a[i] * w[j];
            }
        }
        #pragma unroll
        for (int i = 0; i < 4; i++)
            #pragma unroll
            for (int j = 0; j < 4; j++)
                dt[(ty * 4 + i) * 65 + tx * 4 + j] = acc[i][j];
        __syncthreads();

        // selection: thread (r, q) scans cols cb+q*16 .. +15 of row r
        float4 xq0 = *(const float4*)&xxb[cb + q * 16];
        float4 xq1 = *(const float4*)&xxb[cb + q * 16 + 4];
        float4 xq2 = *(const float4*)&xxb[cb + q * 16 + 8];
        float4 xq3 = *(const float4*)&xxb[cb + q * 16 + 12];
        float xq[16] = {xq0.x, xq0.y, xq0.z, xq0.w, xq1.x, xq1.y, xq1.z, xq1.w,
                        xq2.x, xq2.y, xq2.z, xq2.w, xq3.x, xq3.y, xq3.z, xq3.w};
        #pragma unroll
        for (int j = 0; j < 16; j++) {
            float a = dt[r * 65 + q * 16 + j];
            float v = 2.f * a - xxn - xq[j];
            if (v > t20v[19]) {
                int col = cb + q * 16 + j;
                #pragma unroll
                for (int jj = 19; jj >= 1; --jj) {
                    bool sh  = v > t20v[jj - 1];
                    bool in_ = !sh && (v > t20v[jj]);
                    t20v[jj] = sh ? t20v[jj - 1] : (in_ ? v : t20v[jj]);
                    t20c[jj] = sh ? t20c[jj - 1] : (in_ ? col : t20c[jj]);
                }
                bool i0 = v > t20v[0];
                t20v[0] = i0 ? v : t20v[0];
                t20c[0] = i0 ? col : t20c[0];
            }
        }
    }

    // lists -> LDS (overwrites As/Bs/dt; all selection reads done)
    __syncthreads();
    #pragma unroll
    for (int i = 0; i < 20; i++) {
        Mv[(q * 20 + i) * 64 + r] = t20v[i];
        Mc[(q * 20 + i) * 64 + r] = (ushort)t20c[i];
    }
    __syncthreads();

    // in-block merge of the 4 q-lists -> one top-20 per (row, group)
    if (tid < 64) {
        float hv0 = Mv[ 0 * 64 + r], hv1 = Mv[20 * 64 + r],
              hv2 = Mv[40 * 64 + r], hv3 = Mv[60 * 64 + r];
        int   hc0 = Mc[ 0 * 64 + r], hc1 = Mc[20 * 64 + r],
              hc2 = Mc[40 * 64 + r], hc3 = Mc[60 * 64 + r];
        int n0 = 1, n1 = 1, n2 = 1, n3 = 1;
        size_t p = (size_t)b * N_ + brow + r;
        #pragma unroll 1
        for (int it = 0; it < KNN; it++) {
            float bv = hv0; int bc = hc0; int bq = 0;
            if (hv1 > bv || (hv1 == bv && hc1 < bc)) { bv = hv1; bc = hc1; bq = 1; }
            if (hv2 > bv || (hv2 == bv && hc2 < bc)) { bv = hv2; bc = hc2; bq = 2; }
            if (hv3 > bv || (hv3 == bv && hc3 < bc)) { bv = hv3; bc = hc3; bq = 3; }
            lv[(size_t)(cg * 20 + it) * P_ + p] = bv;
            lc[(size_t)(cg * 20 + it) * P_ + p] = bc;
            if (bq == 0)      { hv0 = (n0 < 20) ? Mv[n0 * 64 + r] : -3.4e38f;        hc0 = (n0 < 20) ? Mc[n0 * 64 + r] : 0;        n0++; }
            else if (bq == 1) { hv1 = (n1 < 20) ? Mv[(20 + n1) * 64 + r] : -3.4e38f; hc1 = (n1 < 20) ? Mc[(20 + n1) * 64 + r] : 0; n1++; }
            else if (bq == 2) { hv2 = (n2 < 20) ? Mv[(40 + n2) * 64 + r] : -3.4e38f; hc2 = (n2 < 20) ? Mc[(40 + n2) * 64 + r] : 0; n2++; }
            else              { hv3 = (n3 < 20) ? Mv[(60 + n3) * 64 + r] : -3.4e38f; hc3 = (n3 < 20) ? Mc[(60 + n3) * 64 + r] : 0; n3++; }
        }
    }
}

// ---------------- merge 4 sorted per-group top-20 lists -> final top-20 -----
// Named scalars only (no runtime-indexed register arrays — rule #20).
__global__ void topk_merge(const float* __restrict__ lv, const int* __restrict__ lc,
                           int* __restrict__ idx) {
    int p = blockIdx.x * 256 + threadIdx.x;
    if (p >= P_) return;
    const float* Lv = lv + p;
    const int*   Lc = lc + p;
    float hv0 = Lv[0], hv1 = Lv[20 * P_], hv2 = Lv[40 * P_], hv3 = Lv[60 * P_];
    int   hc0 = Lc[0], hc1 = Lc[20 * P_], hc2 = Lc[40 * P_], hc3 = Lc[60 * P_];
    int n0 = 1, n1 = 1, n2 = 1, n3 = 1;
    int* out = idx + (size_t)p * KNN;
    #pragma unroll 1
    for (int it = 0; it < KNN; it++) {
        float bv = hv0; int bc = hc0; int bq = 0;
        if (hv1 > bv || (hv1 == bv && hc1 < bc)) { bv = hv1; bc = hc1; bq = 1; }
        if (hv2 > bv || (hv2 == bv && hc2 < bc)) { bv = hv2; bc = hc2; bq = 2; }
        if (hv3 > bv || (hv3 == bv && hc3 < bc)) { bv = hv3; bc = hc3; bq = 3; }
        out[it] = bc;
        if (bq == 0) {
            hv0 = (n0 < 20) ? Lv[(size_t)n0 * P_] : -3.4e38f;
            hc0 = (n0 < 20) ? Lc[(size_t)n0 * P_] : 0;
            n0++;
        } else if (bq == 1) {
            hv1 = (n1 < 20) ? Lv[(size_t)(20 + n1) * P_] : -3.4e38f;
            hc1 = (n1 < 20) ? Lc[(size_t)(20 + n1) * P_] : 0;
            n1++;
        } else if (bq == 2) {
            hv2 = (n2 < 20) ? Lv[(size_t)(40 + n2) * P_] : -3.4e38f;
            hc2 = (n2 < 20) ? Lc[(size_t)(40 + n2) * P_] : 0;
            n2++;
        } else {
            hv3 = (n3 < 20) ? Lv[(size_t)(60 + n3) * P_] : -3.4e38f;
            hc3 = (n3 < 20) ? Lc[(size_t)(60 + n3) * P_] : 0;
            n3++;
        }
    }
}

// ---------------- fp32 GEMM (layer-1 uv only, K=3) --------------------------
__global__ void gemm_wt(const float* __restrict__ A, int lda,
                        const float* __restrict__ W, int ldw,
                        float* __restrict__ out, int ldo, int K) {
    __shared__ float As[16][68];
    __shared__ float Ws[16][68];
    int m0 = blockIdx.y * 64, n0 = blockIdx.x * 64;
    int tid = threadIdx.x;
    int tx = tid & 15, ty = tid >> 4;
    float acc[4][4] = {};
    for (int k0 = 0; k0 < K; k0 += 16) {
        for (int l = tid; l < 1024; l += 256) {
            int r = l >> 4, kk = l & 15, kg = k0 + kk;
            As[kk][r] = (kg < K) ? A[(size_t)(m0 + r) * lda + kg] : 0.f;
            Ws[kk][r] = (kg < K) ? W[(size_t)(n0 + r) * ldw + kg] : 0.f;
        }
        __syncthreads();
        #pragma unroll
        for (int kk = 0; kk < 16; kk++) {
            float4 a4 = *(const float4*)&As[kk][ty * 4];
            float4 w4 = *(const float4*)&Ws[kk][tx * 4];
            float a[4] = {a4.x, a4.y, a4.z, a4.w};
            float w[4] = {w4.x, w4.y, w4.z, w4.w};
            #pragma unroll
            for (int i = 0; i < 4; i++)
                #pragma unroll
                for (int j = 0; j < 4; j++) acc[i][j] += a[i] * w[j];
        }
        __syncthreads();
    }
    for (int i = 0; i < 4; i++) {
        int m = m0 + ty * 4 + i;
        for (int j = 0; j < 4; j++) {
            int n = n0 + tx * 4 + j;
            out[(size_t)m * ldo + n] = acc[i][j];
        }
    }
}

// ---------------- unified split-bf16 MFMA GEMM ------------------------------
// MODE 0: uv; MODE 2: final conv + fused transposed col stats.
// Bijective XCD swizzle (R12): each XCD owns a contiguous y-band.
template<int MODE>
__global__ __launch_bounds__(256, 2)
void gemm_mfma(const ushort* __restrict__ A, const ushort* __restrict__ Bw,
               int K, int nkt, float* __restrict__ out, int ldo,
               float* __restrict__ part) {
    __shared__ ushort lA[128 * 64];
    __shared__ ushort lB[128 * 64];
    int tid = threadIdx.x;
    int lane = tid & 63;
    int wid = tid >> 6;
    int wr = wid >> 1, wc = wid & 1;

    int nx = gridDim.x;
    int ypb = gridDim.y >> 3;
    int bid = blockIdx.y * nx + blockIdx.x;
    int xcd = bid & 7, pos = bid >> 3;
    int yy = xcd * ypb + pos / nx;
    int xx2 = pos % nx;
    int m0 = yy * 128, n0 = xx2 * 128;

    const ushort* pA = A + (size_t)m0 * K;
    const ushort* pB = Bw + (size_t)n0 * K;
    int rowu = tid >> 3, kcu = (tid & 7) * 8;

    f32x4 acc[4][4] = {};
    short8v ra[4], rb[4];
    #pragma unroll
    for (int j = 0; j < 4; j++) {
        int row = rowu + j * 32;
        ra[j] = *(const short8v*)(pA + (size_t)row * K + kcu);
        rb[j] = *(const short8v*)(pB + (size_t)row * K + kcu);
    }

    for (int kt = 0; kt < nkt; kt++) {
        __syncthreads();
        #pragma unroll
        for (int j = 0; j < 4; j++) {
            int row = rowu + j * 32;
            int off = (row * 128 + kcu * 2) ^ ((row & 7) << 4);
            *(short8v*)((char*)lA + off) = ra[j];
            *(short8v*)((char*)lB + off) = rb[j];
        }
        __syncthreads();
        if (kt < nkt - 1) {
            int kbase = (kt + 1) * 64 + kcu;
            #pragma unroll
            for (int j = 0; j < 4; j++) {
                int row = rowu + j * 32;
                ra[j] = *(const short8v*)(pA + (size_t)row * K + kbase);
                rb[j] = *(const short8v*)(pB + (size_t)row * K + kbase);
            }
        }
        #pragma unroll
        for (int ks = 0; ks < 2; ks++) {
            short8v af[4], bg[4];
            int kb2 = (ks * 32 + ((lane >> 4) << 3)) * 2;
            #pragma unroll
            for (int mb = 0; mb < 4; mb++) {
                int row = wr * 64 + mb * 16 + (lane & 15);
                int off = (row * 128 + kb2) ^ ((row & 7) << 4);
                af[mb] = *(const short8v*)((const char*)lA + off);
            }
            #pragma unroll
            for (int nb = 0; nb < 4; nb++) {
                int row = wc * 64 + nb * 16 + (lane & 15);
                int off = (row * 128 + kb2) ^ ((row & 7) << 4);
                bg[nb] = *(const short8v*)((const char*)lB + off);
            }
            #pragma unroll
            for (int mb = 0; mb < 4; mb++)
                #pragma unroll
                for (int nb = 0; nb < 4; nb++)
                    acc[mb][nb] = __builtin_amdgcn_mfma_f32_16x16x32_bf16(af[mb], bg[nb], acc[mb][nb], 0, 0, 0);
        }
    }

    int rbase = m0 + wr * 64 + ((lane >> 4) << 2);
    int cbase = n0 + wc * 64 + (lane & 15);

    if (MODE == 0) {
        #pragma unroll
        for (int mb = 0; mb < 4; mb++)
            #pragma unroll
            for (int nb = 0; nb < 4; nb++)
                #pragma unroll
                for (int r = 0; r < 4; r++)
                    out[(size_t)(rbase + mb * 16 + r) * ldo + cbase + nb * 16] = acc[mb][nb][r];
    } else {
        float* smS = (float*)lA;
        float* smQ = (float*)lB;
        __syncthreads();
        #pragma unroll
        for (int nb = 0; nb < 4; nb++) {
            float s = 0.f, q = 0.f;
            #pragma unroll
            for (int mb = 0; mb < 4; mb++)
                #pragma unroll
                for (int r = 0; r < 4; r++) {
                    float v = acc[mb][nb][r];
                    out[(size_t)(rbase + mb * 16 + r) * ldo + cbase + nb * 16] = v;
                    s += v; q += v * v;
                }
            s += __shfl_xor(s, 16, 64); s += __shfl_xor(s, 32, 64);
            q += __shfl_xor(q, 16, 64); q += __shfl_xor(q, 32, 64);
            if ((lane >> 4) == 0) {
                smS[wid * 64 + nb * 16 + lane] = s;
                smQ[wid * 64 + nb * 16 + lane] = q;
            }
        }
        __syncthreads();
        if (tid < 128) {
            int wcs = tid >> 6, c = tid & 63;
            float s = smS[wcs * 64 + c] + smS[(2 + wcs) * 64 + c];
            float q = smQ[wcs * 64 + c] + smQ[(2 + wcs) * 64 + c];
            int col = n0 + wcs * 64 + c;
            part[(size_t)col * 128 + yy] = s;
            part[131072 + (size_t)col * 128 + yy] = q;
        }
    }
}

// ---------------- gather neighbors, per-(p,o) max/min, per-channel stats ----
__global__ void gather_stats(const float* __restrict__ uv, const int* __restrict__ idx, int O,
                             float* __restrict__ ymax, float* __restrict__ ymin,
                             double* __restrict__ part, int ppb) {
    __shared__ double sd[256], sd2[256];
    int t = threadIdx.x;
    int R = 256 / O;
    int o = t % O;
    int q = t / O;
    double s = 0.0, s2 = 0.0;
    int p0 = blockIdx.x * ppb;
    int ld = 2 * O;
    for (int lp = q; lp < ppb; lp += R) {
        int p = p0 + lp;
        int b = p >> 10;
        const int* ir = idx + (size_t)p * KNN;
        float v = uv[(size_t)p * ld + O + o];
        float mx = -3.4e38f, mn = 3.4e38f;
        for (int kk = 0; kk < KNN; kk++) {
            int j = ir[kk];
            float u = uv[((size_t)((b << 10) + j)) * ld + o];
            float y = u + v;
            mx = fmaxf(mx, y); mn = fminf(mn, y);
            s += (double)y; s2 += (double)y * (double)y;
        }
        ymax[(size_t)p * O + o] = mx;
        ymin[(size_t)p * O + o] = mn;
    }
    sd[t] = s; sd2[t] = s2;
    __syncthreads();
    if (t < O) {
        double a = 0.0, a2 = 0.0;
        for (int qq = 0; qq < R; qq++) { a += sd[qq * O + t]; a2 += sd2[qq * O + t]; }
        part[(size_t)t * 1024 + blockIdx.x] = a;
        part[(size_t)(O + t) * 1024 + blockIdx.x] = a2;
    }
}

// ---------------- parallel finalize: one block per channel ------------------
__global__ void finalize_t(const double* __restrict__ part, int O,
                           const float* __restrict__ g, const float* __restrict__ bt,
                           float* __restrict__ scale, float* __restrict__ shift, double invCount) {
    __shared__ double sa[4], sb[4];
    int o = blockIdx.x;
    int t = threadIdx.x;
    int lane = t & 63, w = t >> 6;
    const double* ps = part + (size_t)o * 1024;
    const double* pq = part + (size_t)(O + o) * 1024;
    double s = 0.0, s2 = 0.0;
    #pragma unroll
    for (int b = 0; b < 4; b++) { s += ps[t + b * 256]; s2 += pq[t + b * 256]; }
    #pragma unroll
    for (int off = 32; off > 0; off >>= 1) { s += __shfl_xor(s, off, 64); s2 += __shfl_xor(s2, off, 64); }
    if (lane == 0) { sa[w] = s; sb[w] = s2; }
    __syncthreads();
    if (t == 0) {
        s = sa[0] + sa[1] + sa[2] + sa[3];
        s2 = sb[0] + sb[1] + sb[2] + sb[3];
        double mean = s * invCount;
        double var = s2 * invCount - mean * mean;
        if (var < 0.0) var = 0.0;
        float sc = (float)(1.0 / sqrt(var + 1e-5)) * g[o];
        scale[o] = sc;
        shift[o] = bt[o] - (float)mean * sc;
    }
}

// ---------------- parallel finalize for float partials (final conv) ---------
__global__ void finalize_f_t(const float* __restrict__ part,
                             const float* __restrict__ g, const float* __restrict__ bt,
                             float* __restrict__ scale, float* __restrict__ shift, double invCount) {
    __shared__ double sa[2], sb[2];
    int o = blockIdx.x;
    int t = threadIdx.x;   // 128 threads
    int lane = t & 63, w = t >> 6;
    double s  = (double)part[(size_t)o * 128 + t];
    double s2 = (double)part[131072 + (size_t)o * 128 + t];
    #pragma unroll
    for (int off = 32; off > 0; off >>= 1) { s += __shfl_xor(s, off, 64); s2 += __shfl_xor(s2, off, 64); }
    if (lane == 0) { sa[w] = s; sb[w] = s2; }
    __syncthreads();
    if (t == 0) {
        s = sa[0] + sa[1];
        s2 = sb[0] + sb[1];
        double mean = s * invCount;
        double var = s2 * invCount - mean * mean;
        if (var < 0.0) var = 0.0;
        float sc = (float)(1.0 / sqrt(var + 1e-5)) * g[o];
        scale[o] = sc;
        shift[o] = bt[o] - (float)mean * sc;
    }
}

// ---------------- edge conv epilogue: BN + leaky (max over k done) ----------
__global__ void apply_edge(const float* __restrict__ ymax, const float* __restrict__ ymin,
                           const float* __restrict__ scale, const float* __restrict__ shift,
                           float* __restrict__ xcat, int O, int off) {
    int i = blockIdx.x * 256 + threadIdx.x;
    if (i < P_ * O) {
        int p = i / O, o = i % O;
        float sc = scale[o];
        float y = (sc >= 0.f) ? ymax[i] : ymin[i];
        float val = y * sc + shift[o];
        xcat[(size_t)p * 512 + off + o] = LEAKY(val);
    }
}

// ---------------- global max+mean pool with fused BN+leaky ------------------
__global__ void pool_kernel(const float* __restrict__ h, const float* __restrict__ scale,
                            const float* __restrict__ shift, float* __restrict__ pooled) {
    __shared__ float smax[256];
    __shared__ double ssum[256];
    int b = blockIdx.x, og = blockIdx.y;
    int t = threadIdx.x;
    int o = og * 64 + (t & 63);
    int ch = t >> 6;
    float sc = scale[o], sh = shift[o];
    float mx = -3.4e38f;
    double sm = 0.0;
    for (int n = ch * 256; n < ch * 256 + 256; n++) {
        float y = h[((size_t)b * N_ + n) * 1024 + o] * sc + sh;
        y = LEAKY(y);
        mx = fmaxf(mx, y);
        sm += (double)y;
    }
    smax[t] = mx; ssum[t] = sm;
    __syncthreads();
    if (t < 64) {
        for (int c = 1; c < 4; c++) { mx = fmaxf(mx, smax[c * 64 + t]); sm += ssum[c * 64 + t]; }
        pooled[(size_t)b * 2048 + o] = mx;
        pooled[(size_t)b * 2048 + 1024 + o] = (float)(sm * (1.0 / N_));
    }
}

// ---------------- small FC: one wave per output -----------------------------
__global__ void fc_kernel(const float* __restrict__ in, int ldi,
                          const float* __restrict__ w, int ldw,
                          const float* __restrict__ bias,
                          float* __restrict__ out, int M, int Nn, int K) {
    int gw = (blockIdx.x * 256 + threadIdx.x) >> 6;
    int lane = threadIdx.x & 63;
    if (gw >= M * Nn) return;
    int m = gw / Nn, n = gw % Nn;
    const float* a = in + (size_t)m * ldi;
    const float* ww = w + (size_t)n * ldw;
    float s = 0.f;
    for (int kk = lane; kk < K; kk += 64) s += a[kk] * ww[kk];
    #pragma unroll
    for (int off = 32; off > 0; off >>= 1) s += __shfl_xor(s, off, 64);
    if (lane == 0) out[(size_t)m * Nn + n] = s + bias[n];
}

// ---------------- BN over batch axis (M=16) + leaky, in place ---------------
__global__ void bn_rows(float* __restrict__ z, int M, int O,
                        const float* __restrict__ g, const float* __restrict__ bt) {
    int o = blockIdx.x * 256 + threadIdx.x;
    if (o >= O) return;
    double s = 0.0, s2 = 0.0;
    for (int m = 0; m < M; m++) {
        float y = z[(size_t)m * O + o];
        s += (double)y; s2 += (double)y * (double)y;
    }
    double mean = s / M;
    double var = s2 / M - mean * mean;
    if (var < 0.0) var = 0.0;
    float sc = (float)(1.0 / sqrt(var + 1e-5)) * g[o];
    float sh = bt[o] - (float)mean * sc;
    for (int m = 0; m < M; m++) {
        float y = z[(size_t)m * O + o] * sc + sh;
        z[(size_t)m * O + o] = LEAKY(y);
    }
}

extern "C" void kernel_launch(void* const* d_in, const int* in_sizes, int n_in,
                              void* d_out, int out_size, void* d_ws, size_t ws_size,
                              hipStream_t stream) {
    const float* cloud = (const float*)d_in[0];
    const float* wf  = (const float*)d_in[17];
    const float* gf  = (const float*)d_in[19];
    const float* btf = (const float*)d_in[20];
    const float* wl1 = (const float*)d_in[21];
    const float* bl1 = (const float*)d_in[22];
    const float* gl1 = (const float*)d_in[23];
    const float* btl1= (const float*)d_in[24];
    const float* wl2 = (const float*)d_in[25];
    const float* bl2 = (const float*)d_in[26];
    const float* gl2 = (const float*)d_in[27];
    const float* btl2= (const float*)d_in[28];
    const float* wl3 = (const float*)d_in[29];
    const float* bl3 = (const float*)d_in[30];

    // workspace layout (bytes)
    const size_t OFF_XCAT  = 0;                        // 33554432
    const size_t OFF_UV    = 33554432;                 // 33554432 (A2 aliases UV+YMAX)
    const size_t OFF_YMAX  = 67108864;                 // 16777216 (xA alias: 12.6MB max)
    const size_t OFF_YMIN  = 83886080;                 // 16777216 (B2 alias)
    const size_t OFF_DIST  = 100663296;                // 67108864: lv/lc during layers (10.5MB), hraw at end
    const size_t OFF_IDX   = 167772160;                // 1310720
    const size_t OFF_XX    = 169082880;                // 65536
    const size_t OFF_W2    = 169148416;                // 524288
    const size_t OFF_PART  = 169676800;                // 4194304: part doubles (WB2 aliases head)
    const size_t OFF_SCALE = 173871104;                // 4096
    const size_t OFF_SHIFT = 173875200;                // 4096
    const size_t OFF_POOL  = 173879296;                // 131072
    const size_t OFF_Z1    = 174010368;                // 32768
    const size_t OFF_Z2    = 174043136;                // 16384
    const size_t TOTAL     = 174059520;
    if (ws_size < TOTAL) return;

    char* ws = (char*)d_ws;
    float* xcat  = (float*)(ws + OFF_XCAT);
    float* uv    = (float*)(ws + OFF_UV);
    float* ymax  = (float*)(ws + OFF_YMAX);
    float* ymin  = (float*)(ws + OFF_YMIN);
    float* hraw  = (float*)(ws + OFF_DIST);
    float* lv    = (float*)(ws + OFF_DIST);            // 4*20*P_*4 = 5242880
    int*   lc    = (int*)  (ws + OFF_DIST + 5242880);  // 5242880
    ushort* A2   = (ushort*)(ws + OFF_UV);
    ushort* B2   = (ushort*)(ws + OFF_YMIN);
    ushort* xA   = (ushort*)(ws + OFF_YMAX);
    ushort* WB2  = (ushort*)(ws + OFF_PART);
    int*   idx   = (int*)  (ws + OFF_IDX);
    float* xx    = (float*)(ws + OFF_XX);
    float* W2    = (float*)(ws + OFF_W2);
    double* part = (double*)(ws + OFF_PART);
    float* partf = (float*)(ws + OFF_PART);
    float* scale = (float*)(ws + OFF_SCALE);
    float* shift = (float*)(ws + OFF_SHIFT);
    float* pooled= (float*)(ws + OFF_POOL);
    float* z1    = (float*)(ws + OFF_Z1);
    float* z2    = (float*)(ws + OFF_Z2);

    const int Cs[4]   = {3, 64, 64, 128};
    const int Os[4]   = {64, 64, 128, 256};
    const int offs[4] = {0, 64, 128, 256};

    for (int L = 0; L < 4; L++) {
        int C = Cs[L], O = Os[L];
        const float* w  = (const float*)d_in[1 + 4 * L];
        const float* g  = (const float*)d_in[3 + 4 * L];
        const float* bt = (const float*)d_in[4 + 4 * L];
        const float* x  = (L == 0) ? cloud : (xcat + offs[L - 1]);
        int lda = (L == 0) ? 3 : 512;

        sqnorm<<<(P_ + 255) / 256, 256, 0, stream>>>(x, lda, C, xx);
        if (C == 3)
            dist_topk_fused<3><<<dim3(16, 4, 16), 256, 0, stream>>>(x, lda, xx, lv, lc);
        else if (C == 64)
            dist_topk_fused<64><<<dim3(16, 4, 16), 256, 0, stream>>>(x, lda, xx, lv, lc);
        else
            dist_topk_fused<128><<<dim3(16, 4, 16), 256, 0, stream>>>(x, lda, xx, lv, lc);
        topk_merge<<<P_ / 256, 256, 0, stream>>>(lv, lc, idx);

        if (L == 0) {
            prep_w2<<<(2 * O * C + 255) / 256, 256, 0, stream>>>(w, W2, O, C);
            gemm_wt<<<dim3(2 * O / 64, P_ / 64), 256, 0, stream>>>(x, lda, W2, C, uv, 2 * O, C);
        } else {
            int K3 = 3 * C, nkt = K3 / 64;
            conv_split<<<(P_ * (C / 4) + 255) / 256, 256, 0, stream>>>(x, lda, C, P_, xA, 0);
            prep_w2_split<<<(2 * O * (C / 4) + 255) / 256, 256, 0, stream>>>(w, WB2, O, C);
            gemm_mfma<0><<<dim3(2 * O / 128, 128), 256, 0, stream>>>(xA, WB2, K3, nkt, uv, 2 * O, nullptr);
        }

        gather_stats<<<1024, 256, 0, stream>>>(uv, idx, O, ymax, ymin, part, 16);
        finalize_t<<<O, 256, 0, stream>>>(part, O, g, bt, scale, shift, 1.0 / ((double)P_ * KNN));
        apply_edge<<<(P_ * O + 255) / 256, 256, 0, stream>>>(ymax, ymin, scale, shift, xcat, O, offs[L]);
    }

    // final 1x1 conv via split-bf16 MFMA GEMM with fused (transposed) col stats
    conv_split<<<(P_ * 128 + 255) / 256, 256, 0, stream>>>(xcat, 512, 512, P_, A2, 0);
    conv_split<<<(1024 * 128 + 255) / 256, 256, 0, stream>>>(wf, 512, 512, 1024, B2, 1);
    gemm_mfma<2><<<dim3(8, 128), 256, 0, stream>>>(A2, B2, 1536, 24, hraw, 1024, partf);

    finalize_f_t<<<1024, 128, 0, stream>>>(partf, gf, btf, scale, shift, 1.0 / (double)P_);
    pool_kernel<<<dim3(16, 16), 256, 0, stream>>>(hraw, scale, shift, pooled);

    // MLP head
    fc_kernel<<<(16 * 512 * 64) / 256, 256, 0, stream>>>(pooled, 2048, wl1, 2048, bl1, z1, 16, 512, 2048);
    bn_rows<<<2, 256, 0, stream>>>(z1, 16, 512, gl1, btl1);
    fc_kernel<<<(16 * 256 * 64) / 256, 256, 0, stream>>>(z1, 512, wl2, 512, bl2, z2, 16, 256, 512);
    bn_rows<<<1, 256, 0, stream>>>(z2, 16, 256, gl2, btl2);
    fc_kernel<<<(16 * 40 * 64 + 255) / 256, 256, 0, stream>>>(z2, 256, wl3, 256, bl3, (float*)d_out, 16, 40, 256);
}

// Round 16
// 796.057 us; speedup vs baseline: 1.5821x; 1.1817x over previous
//
#include <hip/hip_runtime.h>

#define LEAKY(v) ((v) >= 0.f ? (v) : 0.2f*(v))

static const int B_ = 16;
static const int N_ = 1024;
static const int P_ = 16384;   // B*N
static const int KNN = 20;

typedef __attribute__((ext_vector_type(8))) short short8v;
typedef __attribute__((ext_vector_type(4))) float f32x4;

__device__ inline ushort f2bf(float f) {
    unsigned u = __float_as_uint(f);
    unsigned r = u + 0x7FFFu + ((u >> 16) & 1u);
    return (ushort)(r >> 16);
}
__device__ inline float bf2f(ushort h) {
    return __uint_as_float(((unsigned)h) << 16);
}

// ---------------- prep: W2 = [wA ; wB - wA] fp32 (layer-1 only) -------------
__global__ void prep_w2(const float* __restrict__ w, float* __restrict__ W2, int O, int C) {
    int i = blockIdx.x * 256 + threadIdx.x;
    int total = 2 * O * C;
    if (i < total) {
        int row = i / C, c = i % C;
        float val;
        if (row < O) val = w[row * 2 * C + c];
        else { int o = row - O; val = w[o * 2 * C + C + c] - w[o * 2 * C + c]; }
        W2[i] = val;
    }
}

// ---------------- prep W2 and split to bf16 [h|l|h] in one pass (L>=1) ------
__global__ void prep_w2_split(const float* __restrict__ w, ushort* __restrict__ WB2, int O, int C) {
    int i = blockIdx.x * 256 + threadIdx.x;
    int cpr = C >> 2;
    if (i >= 2 * O * cpr) return;
    int row = i / cpr, c4 = (i % cpr) * 4;
    float vv[4];
    #pragma unroll
    for (int j = 0; j < 4; j++) {
        int c = c4 + j;
        if (row < O) vv[j] = w[row * 2 * C + c];
        else { int o = row - O; vv[j] = w[o * 2 * C + C + c] - w[o * 2 * C + c]; }
    }
    ushort4 h, l;
    h.x = f2bf(vv[0]); l.x = f2bf(vv[0] - bf2f(h.x));
    h.y = f2bf(vv[1]); l.y = f2bf(vv[1] - bf2f(h.y));
    h.z = f2bf(vv[2]); l.z = f2bf(vv[2] - bf2f(h.z));
    h.w = f2bf(vv[3]); l.w = f2bf(vv[3] - bf2f(h.w));
    ushort* rowp = WB2 + (size_t)row * 3 * C + c4;
    *(ushort4*)(rowp)         = h;
    *(ushort4*)(rowp + C)     = l;
    *(ushort4*)(rowp + 2 * C) = h;
}

// ---------------- squared norms ----------------
__global__ void sqnorm(const float* __restrict__ x, int lda, int C, float* __restrict__ xx) {
    int p = blockIdx.x * 256 + threadIdx.x;
    if (p < P_) {
        const float* r = x + (size_t)p * lda;
        float s = 0.f;
        for (int c = 0; c < C; c++) s += r[c] * r[c];
        xx[p] = s;
    }
}

// ---------------- fp32 -> split-bf16 rows. mode0: [h|h|l], mode1: [h|l|h] ---
__global__ void conv_split(const float* __restrict__ src, int ld, int C, int rows,
                           ushort* __restrict__ dst, int mode) {
    int i = blockIdx.x * 256 + threadIdx.x;
    int cpr = C >> 2;
    if (i >= rows * cpr) return;
    int p = i / cpr, c4 = (i % cpr) * 4;
    float4 v = *(const float4*)(src + (size_t)p * ld + c4);
    ushort4 h, l;
    h.x = f2bf(v.x); l.x = f2bf(v.x - bf2f(h.x));
    h.y = f2bf(v.y); l.y = f2bf(v.y - bf2f(h.y));
    h.z = f2bf(v.z); l.z = f2bf(v.z - bf2f(h.z));
    h.w = f2bf(v.w); l.w = f2bf(v.w - bf2f(h.w));
    ushort* row = dst + (size_t)p * 3 * C + c4;
    if (mode == 0) {
        *(ushort4*)(row)         = h;
        *(ushort4*)(row + C)     = h;
        *(ushort4*)(row + 2 * C) = l;
    } else {
        *(ushort4*)(row)         = h;
        *(ushort4*)(row + C)     = l;
        *(ushort4*)(row + 2 * C) = h;
    }
}

// ---------------- fp32 dist (all layers): 2*dot - xx_n - xx_m ---------------
// 64x64 tile, 4x4/thread, LDS-transposed mirror store; triangular linear grid.
// fp32 mandatory: split-bf16 dist flips near-tie kNN (R3).
__global__ void dist_kernel(const float* __restrict__ x, int lda, int C,
                            const float* __restrict__ xx, float* __restrict__ dist) {
    int t = blockIdx.x;
    int mi = (int)((sqrtf(8.f * (float)t + 1.f) - 1.f) * 0.5f);
    while ((mi + 1) * (mi + 2) / 2 <= t) mi++;
    while (mi * (mi + 1) / 2 > t) mi--;
    int nj = t - mi * (mi + 1) / 2;
    int m0 = mi * 64, n0 = nj * 64;
    __shared__ float As[16][68];
    __shared__ float Bs[16][68];
    __shared__ float Ts[64][68];
    int b = blockIdx.y;
    const float* xb = x + (size_t)b * N_ * lda;
    int tid = threadIdx.x;
    int tx = tid & 15, ty = tid >> 4;
    float acc[4][4] = {};
    for (int k0 = 0; k0 < C; k0 += 16) {
        for (int l = tid; l < 1024; l += 256) {
            int r = l >> 4, kk = l & 15, kg = k0 + kk;
            As[kk][r] = (kg < C) ? xb[(size_t)(n0 + r) * lda + kg] : 0.f;
            Bs[kk][r] = (kg < C) ? xb[(size_t)(m0 + r) * lda + kg] : 0.f;
        }
        __syncthreads();
        #pragma unroll
        for (int kk = 0; kk < 16; kk++) {
            float4 a4 = *(const float4*)&As[kk][ty * 4];
            float4 w4 = *(const float4*)&Bs[kk][tx * 4];
            float a[4] = {a4.x, a4.y, a4.z, a4.w};
            float w[4] = {w4.x, w4.y, w4.z, w4.w};
            #pragma unroll
            for (int i = 0; i < 4; i++)
                #pragma unroll
                for (int j = 0; j < 4; j++) acc[i][j] += a[i] * w[j];
        }
        __syncthreads();
    }
    size_t prow = (size_t)b * N_;
    #pragma unroll
    for (int i = 0; i < 4; i++) {
        int n = n0 + ty * 4 + i;
        float xn = xx[b * N_ + n];
        float4 v4;
        float vt[4];
        #pragma unroll
        for (int j = 0; j < 4; j++) {
            int m = m0 + tx * 4 + j;
            float v = 2.f * acc[i][j] - xn - xx[b * N_ + m];
            vt[j] = v;
            Ts[tx * 4 + j][ty * 4 + i] = v;   // Ts[m - m0][n - n0]
        }
        v4.x = vt[0]; v4.y = vt[1]; v4.z = vt[2]; v4.w = vt[3];
        *(float4*)&dist[(prow + n) * N_ + m0 + tx * 4] = v4;
    }
    if (m0 != n0) {
        __syncthreads();
        #pragma unroll
        for (int i = 0; i < 4; i++) {
            int mi2 = ty * 4 + i;
            float4 v4 = *(const float4*)&Ts[mi2][tx * 4];
            *(float4*)&dist[(prow + m0 + mi2) * N_ + n0 + tx * 4] = v4;
        }
    }
}

// ---------------- top-k=20 per row; one wave per row ------------------------
// R12 counters showed VGPR=24: the dv[16]/dc[16] ARRAYS spilled to scratch
// despite static indexing (75us x4 = 300us). Same verified algorithm (R8
// bitonic + head-extract), but on 16+16 NAMED scalars — the allocator cannot
// put named scalars in scratch without an explicit spill decision.
#define CE(a,b,up) { bool p_ = (v##b > v##a) || (v##b == v##a && c##b < c##a); \
                     bool s_ = (up) ? p_ : !p_; \
                     float tv_ = v##a; int tc_ = c##a; \
                     v##a = s_ ? v##b : v##a; c##a = s_ ? c##b : c##a; \
                     v##b = s_ ? tv_ : v##b;  c##b = s_ ? tc_ : c##b; }
__global__ void topk_kernel(const float* __restrict__ dist, int* __restrict__ idx) {
    int wave = (blockIdx.x * 256 + threadIdx.x) >> 6;
    int lane = threadIdx.x & 63;
    if (wave >= P_) return;
    const float* row = dist + (size_t)wave * N_;
    int cb = lane * 4;
    float4 q0 = *(const float4*)&row[cb];
    float4 q1 = *(const float4*)&row[256 + cb];
    float4 q2 = *(const float4*)&row[512 + cb];
    float4 q3 = *(const float4*)&row[768 + cb];
    float v0 = q0.x, v1 = q0.y, v2 = q0.z, v3 = q0.w;
    float v4 = q1.x, v5 = q1.y, v6 = q1.z, v7 = q1.w;
    float v8 = q2.x, v9 = q2.y, v10 = q2.z, v11 = q2.w;
    float v12 = q3.x, v13 = q3.y, v14 = q3.z, v15 = q3.w;
    int c0 = cb, c1 = cb + 1, c2 = cb + 2, c3 = cb + 3;
    int c4 = 256 + cb, c5 = 256 + cb + 1, c6 = 256 + cb + 2, c7 = 256 + cb + 3;
    int c8 = 512 + cb, c9 = 512 + cb + 1, c10 = 512 + cb + 2, c11 = 512 + cb + 3;
    int c12 = 768 + cb, c13 = 768 + cb + 1, c14 = 768 + cb + 2, c15 = 768 + cb + 3;

    // bitonic sort, best-first by (value desc, col asc) — R8-verified network
    // k=2, j=1
    CE(0,1,true) CE(2,3,false) CE(4,5,true) CE(6,7,false)
    CE(8,9,true) CE(10,11,false) CE(12,13,true) CE(14,15,false)
    // k=4, j=2
    CE(0,2,true) CE(1,3,true) CE(4,6,false) CE(5,7,false)
    CE(8,10,true) CE(9,11,true) CE(12,14,false) CE(13,15,false)
    // k=4, j=1
    CE(0,1,true) CE(2,3,true) CE(4,5,false) CE(6,7,false)
    CE(8,9,true) CE(10,11,true) CE(12,13,false) CE(14,15,false)
    // k=8, j=4
    CE(0,4,true) CE(1,5,true) CE(2,6,true) CE(3,7,true)
    CE(8,12,false) CE(9,13,false) CE(10,14,false) CE(11,15,false)
    // k=8, j=2
    CE(0,2,true) CE(1,3,true) CE(4,6,true) CE(5,7,true)
    CE(8,10,false) CE(9,11,false) CE(12,14,false) CE(13,15,false)
    // k=8, j=1
    CE(0,1,true) CE(2,3,true) CE(4,5,true) CE(6,7,true)
    CE(8,9,false) CE(10,11,false) CE(12,13,false) CE(14,15,false)
    // k=16, j=8
    CE(0,8,true) CE(1,9,true) CE(2,10,true) CE(3,11,true)
    CE(4,12,true) CE(5,13,true) CE(6,14,true) CE(7,15,true)
    // k=16, j=4
    CE(0,4,true) CE(1,5,true) CE(2,6,true) CE(3,7,true)
    CE(8,12,true) CE(9,13,true) CE(10,14,true) CE(11,15,true)
    // k=16, j=2
    CE(0,2,true) CE(1,3,true) CE(4,6,true) CE(5,7,true)
    CE(8,10,true) CE(9,11,true) CE(12,14,true) CE(13,15,true)
    // k=16, j=1
    CE(0,1,true) CE(2,3,true) CE(4,5,true) CE(6,7,true)
    CE(8,9,true) CE(10,11,true) CE(12,13,true) CE(14,15,true)

    int* out = idx + (size_t)wave * KNN;
    #pragma unroll 1
    for (int it = 0; it < KNN; it++) {
        float bv = v0; int bc = c0;
        #pragma unroll
        for (int off = 32; off > 0; off >>= 1) {
            float ov = __shfl_xor(bv, off, 64);
            int   oc = __shfl_xor(bc, off, 64);
            if (ov > bv || (ov == bv && oc < bc)) { bv = ov; bc = oc; }
        }
        if (lane == 0) out[it] = bc;
        int wc = __builtin_amdgcn_readfirstlane(bc);
        bool mine = (c0 == wc);
        v0 = mine ? v1 : v0;   c0 = mine ? c1 : c0;
        v1 = mine ? v2 : v1;   c1 = mine ? c2 : c1;
        v2 = mine ? v3 : v2;   c2 = mine ? c3 : c2;
        v3 = mine ? v4 : v3;   c3 = mine ? c4 : c3;
        v4 = mine ? v5 : v4;   c4 = mine ? c5 : c4;
        v5 = mine ? v6 : v5;   c5 = mine ? c6 : c5;
        v6 = mine ? v7 : v6;   c6 = mine ? c7 : c6;
        v7 = mine ? v8 : v7;   c7 = mine ? c8 : c7;
        v8 = mine ? v9 : v8;   c8 = mine ? c9 : c8;
        v9 = mine ? v10 : v9;  c9 = mine ? c10 : c9;
        v10 = mine ? v11 : v10; c10 = mine ? c11 : c10;
        v11 = mine ? v12 : v11; c11 = mine ? c12 : c11;
        v12 = mine ? v13 : v12; c12 = mine ? c13 : c12;
        v13 = mine ? v14 : v13; c13 = mine ? c14 : c13;
        v14 = mine ? v15 : v14; c14 = mine ? c15 : c14;
        v15 = mine ? -3.4e38f : v15;
    }
}
#undef CE

// ---------------- fp32 GEMM (layer-1 uv only, K=3) --------------------------
__global__ void gemm_wt(const float* __restrict__ A, int lda,
                        const float* __restrict__ W, int ldw,
                        float* __restrict__ out, int ldo, int K) {
    __shared__ float As[16][68];
    __shared__ float Ws[16][68];
    int m0 = blockIdx.y * 64, n0 = blockIdx.x * 64;
    int tid = threadIdx.x;
    int tx = tid & 15, ty = tid >> 4;
    float acc[4][4] = {};
    for (int k0 = 0; k0 < K; k0 += 16) {
        for (int l = tid; l < 1024; l += 256) {
            int r = l >> 4, kk = l & 15, kg = k0 + kk;
            As[kk][r] = (kg < K) ? A[(size_t)(m0 + r) * lda + kg] : 0.f;
            Ws[kk][r] = (kg < K) ? W[(size_t)(n0 + r) * ldw + kg] : 0.f;
        }
        __syncthreads();
        #pragma unroll
        for (int kk = 0; kk < 16; kk++) {
            float4 a4 = *(const float4*)&As[kk][ty * 4];
            float4 w4 = *(const float4*)&Ws[kk][tx * 4];
            float a[4] = {a4.x, a4.y, a4.z, a4.w};
            float w[4] = {w4.x, w4.y, w4.z, w4.w};
            #pragma unroll
            for (int i = 0; i < 4; i++)
                #pragma unroll
                for (int j = 0; j < 4; j++) acc[i][j] += a[i] * w[j];
        }
        __syncthreads();
    }
    for (int i = 0; i < 4; i++) {
        int m = m0 + ty * 4 + i;
        for (int j = 0; j < 4; j++) {
            int n = n0 + tx * 4 + j;
            out[(size_t)m * ldo + n] = acc[i][j];
        }
    }
}

// ---------------- unified split-bf16 MFMA GEMM ------------------------------
// MODE 0: uv; MODE 2: final conv + fused transposed col stats.
// Bijective XCD swizzle (R12): each XCD owns a contiguous y-band.
template<int MODE>
__global__ __launch_bounds__(256, 2)
void gemm_mfma(const ushort* __restrict__ A, const ushort* __restrict__ Bw,
               int K, int nkt, float* __restrict__ out, int ldo,
               float* __restrict__ part) {
    __shared__ ushort lA[128 * 64];
    __shared__ ushort lB[128 * 64];
    int tid = threadIdx.x;
    int lane = tid & 63;
    int wid = tid >> 6;
    int wr = wid >> 1, wc = wid & 1;

    int nx = gridDim.x;
    int ypb = gridDim.y >> 3;
    int bid = blockIdx.y * nx + blockIdx.x;
    int xcd = bid & 7, pos = bid >> 3;
    int yy = xcd * ypb + pos / nx;
    int xx2 = pos % nx;
    int m0 = yy * 128, n0 = xx2 * 128;

    const ushort* pA = A + (size_t)m0 * K;
    const ushort* pB = Bw + (size_t)n0 * K;
    int rowu = tid >> 3, kcu = (tid & 7) * 8;

    f32x4 acc[4][4] = {};
    short8v ra[4], rb[4];
    #pragma unroll
    for (int j = 0; j < 4; j++) {
        int row = rowu + j * 32;
        ra[j] = *(const short8v*)(pA + (size_t)row * K + kcu);
        rb[j] = *(const short8v*)(pB + (size_t)row * K + kcu);
    }

    for (int kt = 0; kt < nkt; kt++) {
        __syncthreads();
        #pragma unroll
        for (int j = 0; j < 4; j++) {
            int row = rowu + j * 32;
            int off = (row * 128 + kcu * 2) ^ ((row & 7) << 4);
            *(short8v*)((char*)lA + off) = ra[j];
            *(short8v*)((char*)lB + off) = rb[j];
        }
        __syncthreads();
        if (kt < nkt - 1) {
            int kbase = (kt + 1) * 64 + kcu;
            #pragma unroll
            for (int j = 0; j < 4; j++) {
                int row = rowu + j * 32;
                ra[j] = *(const short8v*)(pA + (size_t)row * K + kbase);
                rb[j] = *(const short8v*)(pB + (size_t)row * K + kbase);
            }
        }
        #pragma unroll
        for (int ks = 0; ks < 2; ks++) {
            short8v af[4], bg[4];
            int kb2 = (ks * 32 + ((lane >> 4) << 3)) * 2;
            #pragma unroll
            for (int mb = 0; mb < 4; mb++) {
                int row = wr * 64 + mb * 16 + (lane & 15);
                int off = (row * 128 + kb2) ^ ((row & 7) << 4);
                af[mb] = *(const short8v*)((const char*)lA + off);
            }
            #pragma unroll
            for (int nb = 0; nb < 4; nb++) {
                int row = wc * 64 + nb * 16 + (lane & 15);
                int off = (row * 128 + kb2) ^ ((row & 7) << 4);
                bg[nb] = *(const short8v*)((const char*)lB + off);
            }
            #pragma unroll
            for (int mb = 0; mb < 4; mb++)
                #pragma unroll
                for (int nb = 0; nb < 4; nb++)
                    acc[mb][nb] = __builtin_amdgcn_mfma_f32_16x16x32_bf16(af[mb], bg[nb], acc[mb][nb], 0, 0, 0);
        }
    }

    int rbase = m0 + wr * 64 + ((lane >> 4) << 2);
    int cbase = n0 + wc * 64 + (lane & 15);

    if (MODE == 0) {
        #pragma unroll
        for (int mb = 0; mb < 4; mb++)
            #pragma unroll
            for (int nb = 0; nb < 4; nb++)
                #pragma unroll
                for (int r = 0; r < 4; r++)
                    out[(size_t)(rbase + mb * 16 + r) * ldo + cbase + nb * 16] = acc[mb][nb][r];
    } else {
        float* smS = (float*)lA;
        float* smQ = (float*)lB;
        __syncthreads();
        #pragma unroll
        for (int nb = 0; nb < 4; nb++) {
            float s = 0.f, q = 0.f;
            #pragma unroll
            for (int mb = 0; mb < 4; mb++)
                #pragma unroll
                for (int r = 0; r < 4; r++) {
                    float v = acc[mb][nb][r];
                    out[(size_t)(rbase + mb * 16 + r) * ldo + cbase + nb * 16] = v;
                    s += v; q += v * v;
                }
            s += __shfl_xor(s, 16, 64); s += __shfl_xor(s, 32, 64);
            q += __shfl_xor(q, 16, 64); q += __shfl_xor(q, 32, 64);
            if ((lane >> 4) == 0) {
                smS[wid * 64 + nb * 16 + lane] = s;
                smQ[wid * 64 + nb * 16 + lane] = q;
            }
        }
        __syncthreads();
        if (tid < 128) {
            int wcs = tid >> 6, c = tid & 63;
            float s = smS[wcs * 64 + c] + smS[(2 + wcs) * 64 + c];
            float q = smQ[wcs * 64 + c] + smQ[(2 + wcs) * 64 + c];
            int col = n0 + wcs * 64 + c;
            part[(size_t)col * 128 + yy] = s;
            part[131072 + (size_t)col * 128 + yy] = q;
        }
    }
}

// ---------------- gather neighbors, per-(p,o) max/min, per-channel stats ----
__global__ void gather_stats(const float* __restrict__ uv, const int* __restrict__ idx, int O,
                             float* __restrict__ ymax, float* __restrict__ ymin,
                             double* __restrict__ part, int ppb) {
    __shared__ double sd[256], sd2[256];
    int t = threadIdx.x;
    int R = 256 / O;
    int o = t % O;
    int q = t / O;
    double s = 0.0, s2 = 0.0;
    int p0 = blockIdx.x * ppb;
    int ld = 2 * O;
    for (int lp = q; lp < ppb; lp += R) {
        int p = p0 + lp;
        int b = p >> 10;
        const int* ir = idx + (size_t)p * KNN;
        float v = uv[(size_t)p * ld + O + o];
        float mx = -3.4e38f, mn = 3.4e38f;
        for (int kk = 0; kk < KNN; kk++) {
            int j = ir[kk];
            float u = uv[((size_t)((b << 10) + j)) * ld + o];
            float y = u + v;
            mx = fmaxf(mx, y); mn = fminf(mn, y);
            s += (double)y; s2 += (double)y * (double)y;
        }
        ymax[(size_t)p * O + o] = mx;
        ymin[(size_t)p * O + o] = mn;
    }
    sd[t] = s; sd2[t] = s2;
    __syncthreads();
    if (t < O) {
        double a = 0.0, a2 = 0.0;
        for (int qq = 0; qq < R; qq++) { a += sd[qq * O + t]; a2 += sd2[qq * O + t]; }
        part[(size_t)t * 1024 + blockIdx.x] = a;
        part[(size_t)(O + t) * 1024 + blockIdx.x] = a2;
    }
}

// ---------------- parallel finalize: one block per channel ------------------
__global__ void finalize_t(const double* __restrict__ part, int O,
                           const float* __restrict__ g, const float* __restrict__ bt,
                           float* __restrict__ scale, float* __restrict__ shift, double invCount) {
    __shared__ double sa[4], sb[4];
    int o = blockIdx.x;
    int t = threadIdx.x;
    int lane = t & 63, w = t >> 6;
    const double* ps = part + (size_t)o * 1024;
    const double* pq = part + (size_t)(O + o) * 1024;
    double s = 0.0, s2 = 0.0;
    #pragma unroll
    for (int b = 0; b < 4; b++) { s += ps[t + b * 256]; s2 += pq[t + b * 256]; }
    #pragma unroll
    for (int off = 32; off > 0; off >>= 1) { s += __shfl_xor(s, off, 64); s2 += __shfl_xor(s2, off, 64); }
    if (lane == 0) { sa[w] = s; sb[w] = s2; }
    __syncthreads();
    if (t == 0) {
        s = sa[0] + sa[1] + sa[2] + sa[3];
        s2 = sb[0] + sb[1] + sb[2] + sb[3];
        double mean = s * invCount;
        double var = s2 * invCount - mean * mean;
        if (var < 0.0) var = 0.0;
        float sc = (float)(1.0 / sqrt(var + 1e-5)) * g[o];
        scale[o] = sc;
        shift[o] = bt[o] - (float)mean * sc;
    }
}

// ---------------- parallel finalize for float partials (final conv) ---------
__global__ void finalize_f_t(const float* __restrict__ part,
                             const float* __restrict__ g, const float* __restrict__ bt,
                             float* __restrict__ scale, float* __restrict__ shift, double invCount) {
    __shared__ double sa[2], sb[2];
    int o = blockIdx.x;
    int t = threadIdx.x;   // 128 threads
    int lane = t & 63, w = t >> 6;
    double s  = (double)part[(size_t)o * 128 + t];
    double s2 = (double)part[131072 + (size_t)o * 128 + t];
    #pragma unroll
    for (int off = 32; off > 0; off >>= 1) { s += __shfl_xor(s, off, 64); s2 += __shfl_xor(s2, off, 64); }
    if (lane == 0) { sa[w] = s; sb[w] = s2; }
    __syncthreads();
    if (t == 0) {
        s = sa[0] + sa[1];
        s2 = sb[0] + sb[1];
        double mean = s * invCount;
        double var = s2 * invCount - mean * mean;
        if (var < 0.0) var = 0.0;
        float sc = (float)(1.0 / sqrt(var + 1e-5)) * g[o];
        scale[o] = sc;
        shift[o] = bt[o] - (float)mean * sc;
    }
}

// ---------------- edge conv epilogue: BN + leaky (max over k done) ----------
__global__ void apply_edge(const float* __restrict__ ymax, const float* __restrict__ ymin,
                           const float* __restrict__ scale, const float* __restrict__ shift,
                           float* __restrict__ xcat, int O, int off) {
    int i = blockIdx.x * 256 + threadIdx.x;
    if (i < P_ * O) {
        int p = i / O, o = i % O;
        float sc = scale[o];
        float y = (sc >= 0.f) ? ymax[i] : ymin[i];
        float val = y * sc + shift[o];
        xcat[(size_t)p * 512 + off + o] = LEAKY(val);
    }
}

// ---------------- global max+mean pool with fused BN+leaky ------------------
__global__ void pool_kernel(const float* __restrict__ h, const float* __restrict__ scale,
                            const float* __restrict__ shift, float* __restrict__ pooled) {
    __shared__ float smax[256];
    __shared__ double ssum[256];
    int b = blockIdx.x, og = blockIdx.y;
    int t = threadIdx.x;
    int o = og * 64 + (t & 63);
    int ch = t >> 6;
    float sc = scale[o], sh = shift[o];
    float mx = -3.4e38f;
    double sm = 0.0;
    for (int n = ch * 256; n < ch * 256 + 256; n++) {
        float y = h[((size_t)b * N_ + n) * 1024 + o] * sc + sh;
        y = LEAKY(y);
        mx = fmaxf(mx, y);
        sm += (double)y;
    }
    smax[t] = mx; ssum[t] = sm;
    __syncthreads();
    if (t < 64) {
        for (int c = 1; c < 4; c++) { mx = fmaxf(mx, smax[c * 64 + t]); sm += ssum[c * 64 + t]; }
        pooled[(size_t)b * 2048 + o] = mx;
        pooled[(size_t)b * 2048 + 1024 + o] = (float)(sm * (1.0 / N_));
    }
}

// ---------------- small FC: one wave per output -----------------------------
__global__ void fc_kernel(const float* __restrict__ in, int ldi,
                          const float* __restrict__ w, int ldw,
                          const float* __restrict__ bias,
                          float* __restrict__ out, int M, int Nn, int K) {
    int gw = (blockIdx.x * 256 + threadIdx.x) >> 6;
    int lane = threadIdx.x & 63;
    if (gw >= M * Nn) return;
    int m = gw / Nn, n = gw % Nn;
    const float* a = in + (size_t)m * ldi;
    const float* ww = w + (size_t)n * ldw;
    float s = 0.f;
    for (int kk = lane; kk < K; kk += 64) s += a[kk] * ww[kk];
    #pragma unroll
    for (int off = 32; off > 0; off >>= 1) s += __shfl_xor(s, off, 64);
    if (lane == 0) out[(size_t)m * Nn + n] = s + bias[n];
}

// ---------------- BN over batch axis (M=16) + leaky, in place ---------------
__global__ void bn_rows(float* __restrict__ z, int M, int O,
                        const float* __restrict__ g, const float* __restrict__ bt) {
    int o = blockIdx.x * 256 + threadIdx.x;
    if (o >= O) return;
    double s = 0.0, s2 = 0.0;
    for (int m = 0; m < M; m++) {
        float y = z[(size_t)m * O + o];
        s += (double)y; s2 += (double)y * (double)y;
    }
    double mean = s / M;
    double var = s2 / M - mean * mean;
    if (var < 0.0) var = 0.0;
    float sc = (float)(1.0 / sqrt(var + 1e-5)) * g[o];
    float sh = bt[o] - (float)mean * sc;
    for (int m = 0; m < M; m++) {
        float y = z[(size_t)m * O + o] * sc + sh;
        z[(size_t)m * O + o] = LEAKY(y);
    }
}

extern "C" void kernel_launch(void* const* d_in, const int* in_sizes, int n_in,
                              void* d_out, int out_size, void* d_ws, size_t ws_size,
                              hipStream_t stream) {
    const float* cloud = (const float*)d_in[0];
    const float* wf  = (const float*)d_in[17];
    const float* gf  = (const float*)d_in[19];
    const float* btf = (const float*)d_in[20];
    const float* wl1 = (const float*)d_in[21];
    const float* bl1 = (const float*)d_in[22];
    const float* gl1 = (const float*)d_in[23];
    const float* btl1= (const float*)d_in[24];
    const float* wl2 = (const float*)d_in[25];
    const float* bl2 = (const float*)d_in[26];
    const float* gl2 = (const float*)d_in[27];
    const float* btl2= (const float*)d_in[28];
    const float* wl3 = (const float*)d_in[29];
    const float* bl3 = (const float*)d_in[30];

    // workspace layout (bytes)
    const size_t OFF_XCAT  = 0;                        // 33554432
    const size_t OFF_UV    = 33554432;                 // 33554432 (A2 aliases UV+YMAX)
    const size_t OFF_YMAX  = 67108864;                 // 16777216 (xA alias: 12.6MB max)
    const size_t OFF_YMIN  = 83886080;                 // 16777216 (B2 alias)
    const size_t OFF_DIST  = 100663296;                // 67108864 (aliased as hraw)
    const size_t OFF_IDX   = 167772160;                // 1310720
    const size_t OFF_XX    = 169082880;                // 65536
    const size_t OFF_W2    = 169148416;                // 524288
    const size_t OFF_PART  = 169676800;                // 4194304: part doubles (WB2 aliases head)
    const size_t OFF_SCALE = 173871104;                // 4096
    const size_t OFF_SHIFT = 173875200;                // 4096
    const size_t OFF_POOL  = 173879296;                // 131072
    const size_t OFF_Z1    = 174010368;                // 32768
    const size_t OFF_Z2    = 174043136;                // 16384
    const size_t TOTAL     = 174059520;
    if (ws_size < TOTAL) return;

    char* ws = (char*)d_ws;
    float* xcat  = (float*)(ws + OFF_XCAT);
    float* uv    = (float*)(ws + OFF_UV);
    float* ymax  = (float*)(ws + OFF_YMAX);
    float* ymin  = (float*)(ws + OFF_YMIN);
    float* dist  = (float*)(ws + OFF_DIST);
    float* hraw  = (float*)(ws + OFF_DIST);
    ushort* A2   = (ushort*)(ws + OFF_UV);
    ushort* B2   = (ushort*)(ws + OFF_YMIN);
    ushort* xA   = (ushort*)(ws + OFF_YMAX);
    ushort* WB2  = (ushort*)(ws + OFF_PART);
    int*   idx   = (int*)  (ws + OFF_IDX);
    float* xx    = (float*)(ws + OFF_XX);
    float* W2    = (float*)(ws + OFF_W2);
    double* part = (double*)(ws + OFF_PART);
    float* partf = (float*)(ws + OFF_PART);
    float* scale = (float*)(ws + OFF_SCALE);
    float* shift = (float*)(ws + OFF_SHIFT);
    float* pooled= (float*)(ws + OFF_POOL);
    float* z1    = (float*)(ws + OFF_Z1);
    float* z2    = (float*)(ws + OFF_Z2);

    const int Cs[4]   = {3, 64, 64, 128};
    const int Os[4]   = {64, 64, 128, 256};
    const int offs[4] = {0, 64, 128, 256};

    for (int L = 0; L < 4; L++) {
        int C = Cs[L], O = Os[L];
        const float* w  = (const float*)d_in[1 + 4 * L];
        const float* g  = (const float*)d_in[3 + 4 * L];
        const float* bt = (const float*)d_in[4 + 4 * L];
        const float* x  = (L == 0) ? cloud : (xcat + offs[L - 1]);
        int lda = (L == 0) ? 3 : 512;

        sqnorm<<<(P_ + 255) / 256, 256, 0, stream>>>(x, lda, C, xx);
        dist_kernel<<<dim3(136, 16), 256, 0, stream>>>(x, lda, C, xx, dist);
        topk_kernel<<<(P_ * 64) / 256, 256, 0, stream>>>(dist, idx);

        if (L == 0) {
            prep_w2<<<(2 * O * C + 255) / 256, 256, 0, stream>>>(w, W2, O, C);
            gemm_wt<<<dim3(2 * O / 64, P_ / 64), 256, 0, stream>>>(x, lda, W2, C, uv, 2 * O, C);
        } else {
            int K3 = 3 * C, nkt = K3 / 64;
            conv_split<<<(P_ * (C / 4) + 255) / 256, 256, 0, stream>>>(x, lda, C, P_, xA, 0);
            prep_w2_split<<<(2 * O * (C / 4) + 255) / 256, 256, 0, stream>>>(w, WB2, O, C);
            gemm_mfma<0><<<dim3(2 * O / 128, 128), 256, 0, stream>>>(xA, WB2, K3, nkt, uv, 2 * O, nullptr);
        }

        gather_stats<<<1024, 256, 0, stream>>>(uv, idx, O, ymax, ymin, part, 16);
        finalize_t<<<O, 256, 0, stream>>>(part, O, g, bt, scale, shift, 1.0 / ((double)P_ * KNN));
        apply_edge<<<(P_ * O + 255) / 256, 256, 0, stream>>>(ymax, ymin, scale, shift, xcat, O, offs[L]);
    }

    // final 1x1 conv via split-bf16 MFMA GEMM with fused (transposed) col stats
    conv_split<<<(P_ * 128 + 255) / 256, 256, 0, stream>>>(xcat, 512, 512, P_, A2, 0);
    conv_split<<<(1024 * 128 + 255) / 256, 256, 0, stream>>>(wf, 512, 512, 1024, B2, 1);
    gemm_mfma<2><<<dim3(8, 128), 256, 0, stream>>>(A2, B2, 1536, 24, hraw, 1024, partf);

    finalize_f_t<<<1024, 128, 0, stream>>>(partf, gf, btf, scale, shift, 1.0 / (double)P_);
    pool_kernel<<<dim3(16, 16), 256, 0, stream>>>(hraw, scale, shift, pooled);

    // MLP head
    fc_kernel<<<(16 * 512 * 64) / 256, 256, 0, stream>>>(pooled, 2048, wl1, 2048, bl1, z1, 16, 512, 2048);
    bn_rows<<<2, 256, 0, stream>>>(z1, 16, 512, gl1, btl1);
    fc_kernel<<<(16 * 256 * 64) / 256, 256, 0, stream>>>(z1, 512, wl2, 512, bl2, z2, 16, 256, 512);
    bn_rows<<<1, 256, 0, stream>>>(z2, 16, 256, gl2, btl2);
    fc_kernel<<<(16 * 40 * 64 + 255) / 256, 256, 0, stream>>>(z2, 256, wl3, 256, bl3, (float*)d_out, 16, 40, 256);
}

// Round 17
// 740.830 us; speedup vs baseline: 1.7001x; 1.0745x over previous
//
#include <hip/hip_runtime.h>

#define LEAKY(v) ((v) >= 0.f ? (v) : 0.2f*(v))

static const int B_ = 16;
static const int N_ = 1024;
static const int P_ = 16384;   // B*N
static const int KNN = 20;

typedef __attribute__((ext_vector_type(8))) short short8v;
typedef __attribute__((ext_vector_type(4))) float f32x4;

__device__ inline ushort f2bf(float f) {
    unsigned u = __float_as_uint(f);
    unsigned r = u + 0x7FFFu + ((u >> 16) & 1u);
    return (ushort)(r >> 16);
}
__device__ inline float bf2f(ushort h) {
    return __uint_as_float(((unsigned)h) << 16);
}

// ---------------- prep: W2 = [wA ; wB - wA] fp32 (layer-1 only) -------------
__global__ void prep_w2(const float* __restrict__ w, float* __restrict__ W2, int O, int C) {
    int i = blockIdx.x * 256 + threadIdx.x;
    int total = 2 * O * C;
    if (i < total) {
        int row = i / C, c = i % C;
        float val;
        if (row < O) val = w[row * 2 * C + c];
        else { int o = row - O; val = w[o * 2 * C + C + c] - w[o * 2 * C + c]; }
        W2[i] = val;
    }
}

// ---------------- prep W2 and split to bf16 [h|l|h] in one pass (L>=1) ------
__global__ void prep_w2_split(const float* __restrict__ w, ushort* __restrict__ WB2, int O, int C) {
    int i = blockIdx.x * 256 + threadIdx.x;
    int cpr = C >> 2;
    if (i >= 2 * O * cpr) return;
    int row = i / cpr, c4 = (i % cpr) * 4;
    float vv[4];
    #pragma unroll
    for (int j = 0; j < 4; j++) {
        int c = c4 + j;
        if (row < O) vv[j] = w[row * 2 * C + c];
        else { int o = row - O; vv[j] = w[o * 2 * C + C + c] - w[o * 2 * C + c]; }
    }
    ushort4 h, l;
    h.x = f2bf(vv[0]); l.x = f2bf(vv[0] - bf2f(h.x));
    h.y = f2bf(vv[1]); l.y = f2bf(vv[1] - bf2f(h.y));
    h.z = f2bf(vv[2]); l.z = f2bf(vv[2] - bf2f(h.z));
    h.w = f2bf(vv[3]); l.w = f2bf(vv[3] - bf2f(h.w));
    ushort* rowp = WB2 + (size_t)row * 3 * C + c4;
    *(ushort4*)(rowp)         = h;
    *(ushort4*)(rowp + C)     = l;
    *(ushort4*)(rowp + 2 * C) = h;
}

// ---------------- squared norms ----------------
__global__ void sqnorm(const float* __restrict__ x, int lda, int C, float* __restrict__ xx) {
    int p = blockIdx.x * 256 + threadIdx.x;
    if (p < P_) {
        const float* r = x + (size_t)p * lda;
        float s = 0.f;
        for (int c = 0; c < C; c++) s += r[c] * r[c];
        xx[p] = s;
    }
}

// ---------------- fp32 -> split-bf16 rows. mode0: [h|h|l], mode1: [h|l|h] ---
__global__ void conv_split(const float* __restrict__ src, int ld, int C, int rows,
                           ushort* __restrict__ dst, int mode) {
    int i = blockIdx.x * 256 + threadIdx.x;
    int cpr = C >> 2;
    if (i >= rows * cpr) return;
    int p = i / cpr, c4 = (i % cpr) * 4;
    float4 v = *(const float4*)(src + (size_t)p * ld + c4);
    ushort4 h, l;
    h.x = f2bf(v.x); l.x = f2bf(v.x - bf2f(h.x));
    h.y = f2bf(v.y); l.y = f2bf(v.y - bf2f(h.y));
    h.z = f2bf(v.z); l.z = f2bf(v.z - bf2f(h.z));
    h.w = f2bf(v.w); l.w = f2bf(v.w - bf2f(h.w));
    ushort* row = dst + (size_t)p * 3 * C + c4;
    if (mode == 0) {
        *(ushort4*)(row)         = h;
        *(ushort4*)(row + C)     = h;
        *(ushort4*)(row + 2 * C) = l;
    } else {
        *(ushort4*)(row)         = h;
        *(ushort4*)(row + C)     = l;
        *(ushort4*)(row + 2 * C) = h;
    }
}

// ---------------- fp32 dist (all layers): 2*dot - xx_n - xx_m ---------------
// 64x64 tile, 4x4/thread, LDS-transposed mirror store; triangular linear grid.
// fp32 mandatory: split-bf16 dist flips near-tie kNN (R3).
__global__ void dist_kernel(const float* __restrict__ x, int lda, int C,
                            const float* __restrict__ xx, float* __restrict__ dist) {
    int t = blockIdx.x;
    int mi = (int)((sqrtf(8.f * (float)t + 1.f) - 1.f) * 0.5f);
    while ((mi + 1) * (mi + 2) / 2 <= t) mi++;
    while (mi * (mi + 1) / 2 > t) mi--;
    int nj = t - mi * (mi + 1) / 2;
    int m0 = mi * 64, n0 = nj * 64;
    __shared__ float As[16][68];
    __shared__ float Bs[16][68];
    __shared__ float Ts[64][68];
    int b = blockIdx.y;
    const float* xb = x + (size_t)b * N_ * lda;
    int tid = threadIdx.x;
    int tx = tid & 15, ty = tid >> 4;
    float acc[4][4] = {};
    for (int k0 = 0; k0 < C; k0 += 16) {
        for (int l = tid; l < 1024; l += 256) {
            int r = l >> 4, kk = l & 15, kg = k0 + kk;
            As[kk][r] = (kg < C) ? xb[(size_t)(n0 + r) * lda + kg] : 0.f;
            Bs[kk][r] = (kg < C) ? xb[(size_t)(m0 + r) * lda + kg] : 0.f;
        }
        __syncthreads();
        #pragma unroll
        for (int kk = 0; kk < 16; kk++) {
            float4 a4 = *(const float4*)&As[kk][ty * 4];
            float4 w4 = *(const float4*)&Bs[kk][tx * 4];
            float a[4] = {a4.x, a4.y, a4.z, a4.w};
            float w[4] = {w4.x, w4.y, w4.z, w4.w};
            #pragma unroll
            for (int i = 0; i < 4; i++)
                #pragma unroll
                for (int j = 0; j < 4; j++) acc[i][j] += a[i] * w[j];
        }
        __syncthreads();
    }
    size_t prow = (size_t)b * N_;
    #pragma unroll
    for (int i = 0; i < 4; i++) {
        int n = n0 + ty * 4 + i;
        float xn = xx[b * N_ + n];
        float4 v4;
        float vt[4];
        #pragma unroll
        for (int j = 0; j < 4; j++) {
            int m = m0 + tx * 4 + j;
            float v = 2.f * acc[i][j] - xn - xx[b * N_ + m];
            vt[j] = v;
            Ts[tx * 4 + j][ty * 4 + i] = v;   // Ts[m - m0][n - n0]
        }
        v4.x = vt[0]; v4.y = vt[1]; v4.z = vt[2]; v4.w = vt[3];
        *(float4*)&dist[(prow + n) * N_ + m0 + tx * 4] = v4;
    }
    if (m0 != n0) {
        __syncthreads();
        #pragma unroll
        for (int i = 0; i < 4; i++) {
            int mi2 = ty * 4 + i;
            float4 v4 = *(const float4*)&Ts[mi2][tx * 4];
            *(float4*)&dist[(prow + m0 + mi2) * N_ + n0 + tx * 4] = v4;
        }
    }
}

// ---------------- top-k=20 per row; one wave per row ------------------------
// Named scalars (R16: arrays spilled at VGPR=24; named scalars fixed it).
#define CE(a,b,up) { bool p_ = (v##b > v##a) || (v##b == v##a && c##b < c##a); \
                     bool s_ = (up) ? p_ : !p_; \
                     float tv_ = v##a; int tc_ = c##a; \
                     v##a = s_ ? v##b : v##a; c##a = s_ ? c##b : c##a; \
                     v##b = s_ ? tv_ : v##b;  c##b = s_ ? tc_ : c##b; }
__global__ void topk_kernel(const float* __restrict__ dist, int* __restrict__ idx) {
    int wave = (blockIdx.x * 256 + threadIdx.x) >> 6;
    int lane = threadIdx.x & 63;
    if (wave >= P_) return;
    const float* row = dist + (size_t)wave * N_;
    int cb = lane * 4;
    float4 q0 = *(const float4*)&row[cb];
    float4 q1 = *(const float4*)&row[256 + cb];
    float4 q2 = *(const float4*)&row[512 + cb];
    float4 q3 = *(const float4*)&row[768 + cb];
    float v0 = q0.x, v1 = q0.y, v2 = q0.z, v3 = q0.w;
    float v4 = q1.x, v5 = q1.y, v6 = q1.z, v7 = q1.w;
    float v8 = q2.x, v9 = q2.y, v10 = q2.z, v11 = q2.w;
    float v12 = q3.x, v13 = q3.y, v14 = q3.z, v15 = q3.w;
    int c0 = cb, c1 = cb + 1, c2 = cb + 2, c3 = cb + 3;
    int c4 = 256 + cb, c5 = 256 + cb + 1, c6 = 256 + cb + 2, c7 = 256 + cb + 3;
    int c8 = 512 + cb, c9 = 512 + cb + 1, c10 = 512 + cb + 2, c11 = 512 + cb + 3;
    int c12 = 768 + cb, c13 = 768 + cb + 1, c14 = 768 + cb + 2, c15 = 768 + cb + 3;

    // bitonic sort, best-first by (value desc, col asc)
    CE(0,1,true) CE(2,3,false) CE(4,5,true) CE(6,7,false)
    CE(8,9,true) CE(10,11,false) CE(12,13,true) CE(14,15,false)
    CE(0,2,true) CE(1,3,true) CE(4,6,false) CE(5,7,false)
    CE(8,10,true) CE(9,11,true) CE(12,14,false) CE(13,15,false)
    CE(0,1,true) CE(2,3,true) CE(4,5,false) CE(6,7,false)
    CE(8,9,true) CE(10,11,true) CE(12,13,false) CE(14,15,false)
    CE(0,4,true) CE(1,5,true) CE(2,6,true) CE(3,7,true)
    CE(8,12,false) CE(9,13,false) CE(10,14,false) CE(11,15,false)
    CE(0,2,true) CE(1,3,true) CE(4,6,true) CE(5,7,true)
    CE(8,10,false) CE(9,11,false) CE(12,14,false) CE(13,15,false)
    CE(0,1,true) CE(2,3,true) CE(4,5,true) CE(6,7,true)
    CE(8,9,false) CE(10,11,false) CE(12,13,false) CE(14,15,false)
    CE(0,8,true) CE(1,9,true) CE(2,10,true) CE(3,11,true)
    CE(4,12,true) CE(5,13,true) CE(6,14,true) CE(7,15,true)
    CE(0,4,true) CE(1,5,true) CE(2,6,true) CE(3,7,true)
    CE(8,12,true) CE(9,13,true) CE(10,14,true) CE(11,15,true)
    CE(0,2,true) CE(1,3,true) CE(4,6,true) CE(5,7,true)
    CE(8,10,true) CE(9,11,true) CE(12,14,true) CE(13,15,true)
    CE(0,1,true) CE(2,3,true) CE(4,5,true) CE(6,7,true)
    CE(8,9,true) CE(10,11,true) CE(12,13,true) CE(14,15,true)

    int* out = idx + (size_t)wave * KNN;
    #pragma unroll 1
    for (int it = 0; it < KNN; it++) {
        float bv = v0; int bc = c0;
        #pragma unroll
        for (int off = 32; off > 0; off >>= 1) {
            float ov = __shfl_xor(bv, off, 64);
            int   oc = __shfl_xor(bc, off, 64);
            if (ov > bv || (ov == bv && oc < bc)) { bv = ov; bc = oc; }
        }
        if (lane == 0) out[it] = bc;
        int wc = __builtin_amdgcn_readfirstlane(bc);
        bool mine = (c0 == wc);
        v0 = mine ? v1 : v0;   c0 = mine ? c1 : c0;
        v1 = mine ? v2 : v1;   c1 = mine ? c2 : c1;
        v2 = mine ? v3 : v2;   c2 = mine ? c3 : c2;
        v3 = mine ? v4 : v3;   c3 = mine ? c4 : c3;
        v4 = mine ? v5 : v4;   c4 = mine ? c5 : c4;
        v5 = mine ? v6 : v5;   c5 = mine ? c6 : c5;
        v6 = mine ? v7 : v6;   c6 = mine ? c7 : c6;
        v7 = mine ? v8 : v7;   c7 = mine ? c8 : c7;
        v8 = mine ? v9 : v8;   c8 = mine ? c9 : c8;
        v9 = mine ? v10 : v9;  c9 = mine ? c10 : c9;
        v10 = mine ? v11 : v10; c10 = mine ? c11 : c10;
        v11 = mine ? v12 : v11; c11 = mine ? c12 : c11;
        v12 = mine ? v13 : v12; c12 = mine ? c13 : c12;
        v13 = mine ? v14 : v13; c13 = mine ? c14 : c13;
        v14 = mine ? v15 : v14; c14 = mine ? c15 : c14;
        v15 = mine ? -3.4e38f : v15;
    }
}
#undef CE

// ---------------- fp32 GEMM (layer-1 uv only, K=3) --------------------------
__global__ void gemm_wt(const float* __restrict__ A, int lda,
                        const float* __restrict__ W, int ldw,
                        float* __restrict__ out, int ldo, int K) {
    __shared__ float As[16][68];
    __shared__ float Ws[16][68];
    int m0 = blockIdx.y * 64, n0 = blockIdx.x * 64;
    int tid = threadIdx.x;
    int tx = tid & 15, ty = tid >> 4;
    float acc[4][4] = {};
    for (int k0 = 0; k0 < K; k0 += 16) {
        for (int l = tid; l < 1024; l += 256) {
            int r = l >> 4, kk = l & 15, kg = k0 + kk;
            As[kk][r] = (kg < K) ? A[(size_t)(m0 + r) * lda + kg] : 0.f;
            Ws[kk][r] = (kg < K) ? W[(size_t)(n0 + r) * ldw + kg] : 0.f;
        }
        __syncthreads();
        #pragma unroll
        for (int kk = 0; kk < 16; kk++) {
            float4 a4 = *(const float4*)&As[kk][ty * 4];
            float4 w4 = *(const float4*)&Ws[kk][tx * 4];
            float a[4] = {a4.x, a4.y, a4.z, a4.w};
            float w[4] = {w4.x, w4.y, w4.z, w4.w};
            #pragma unroll
            for (int i = 0; i < 4; i++)
                #pragma unroll
                for (int j = 0; j < 4; j++) acc[i][j] += a[i] * w[j];
        }
        __syncthreads();
    }
    for (int i = 0; i < 4; i++) {
        int m = m0 + ty * 4 + i;
        for (int j = 0; j < 4; j++) {
            int n = n0 + tx * 4 + j;
            out[(size_t)m * ldo + n] = acc[i][j];
        }
    }
}

// ---------------- unified split-bf16 MFMA GEMM ------------------------------
// MODE 0: uv; MODE 2: final conv + fused transposed col stats.
// Bijective XCD swizzle (R12): each XCD owns a contiguous y-band.
template<int MODE>
__global__ __launch_bounds__(256, 2)
void gemm_mfma(const ushort* __restrict__ A, const ushort* __restrict__ Bw,
               int K, int nkt, float* __restrict__ out, int ldo,
               float* __restrict__ part) {
    __shared__ ushort lA[128 * 64];
    __shared__ ushort lB[128 * 64];
    int tid = threadIdx.x;
    int lane = tid & 63;
    int wid = tid >> 6;
    int wr = wid >> 1, wc = wid & 1;

    int nx = gridDim.x;
    int ypb = gridDim.y >> 3;
    int bid = blockIdx.y * nx + blockIdx.x;
    int xcd = bid & 7, pos = bid >> 3;
    int yy = xcd * ypb + pos / nx;
    int xx2 = pos % nx;
    int m0 = yy * 128, n0 = xx2 * 128;

    const ushort* pA = A + (size_t)m0 * K;
    const ushort* pB = Bw + (size_t)n0 * K;
    int rowu = tid >> 3, kcu = (tid & 7) * 8;

    f32x4 acc[4][4] = {};
    short8v ra[4], rb[4];
    #pragma unroll
    for (int j = 0; j < 4; j++) {
        int row = rowu + j * 32;
        ra[j] = *(const short8v*)(pA + (size_t)row * K + kcu);
        rb[j] = *(const short8v*)(pB + (size_t)row * K + kcu);
    }

    for (int kt = 0; kt < nkt; kt++) {
        __syncthreads();
        #pragma unroll
        for (int j = 0; j < 4; j++) {
            int row = rowu + j * 32;
            int off = (row * 128 + kcu * 2) ^ ((row & 7) << 4);
            *(short8v*)((char*)lA + off) = ra[j];
            *(short8v*)((char*)lB + off) = rb[j];
        }
        __syncthreads();
        if (kt < nkt - 1) {
            int kbase = (kt + 1) * 64 + kcu;
            #pragma unroll
            for (int j = 0; j < 4; j++) {
                int row = rowu + j * 32;
                ra[j] = *(const short8v*)(pA + (size_t)row * K + kbase);
                rb[j] = *(const short8v*)(pB + (size_t)row * K + kbase);
            }
        }
        #pragma unroll
        for (int ks = 0; ks < 2; ks++) {
            short8v af[4], bg[4];
            int kb2 = (ks * 32 + ((lane >> 4) << 3)) * 2;
            #pragma unroll
            for (int mb = 0; mb < 4; mb++) {
                int row = wr * 64 + mb * 16 + (lane & 15);
                int off = (row * 128 + kb2) ^ ((row & 7) << 4);
                af[mb] = *(const short8v*)((const char*)lA + off);
            }
            #pragma unroll
            for (int nb = 0; nb < 4; nb++) {
                int row = wc * 64 + nb * 16 + (lane & 15);
                int off = (row * 128 + kb2) ^ ((row & 7) << 4);
                bg[nb] = *(const short8v*)((const char*)lB + off);
            }
            #pragma unroll
            for (int mb = 0; mb < 4; mb++)
                #pragma unroll
                for (int nb = 0; nb < 4; nb++)
                    acc[mb][nb] = __builtin_amdgcn_mfma_f32_16x16x32_bf16(af[mb], bg[nb], acc[mb][nb], 0, 0, 0);
        }
    }

    int rbase = m0 + wr * 64 + ((lane >> 4) << 2);
    int cbase = n0 + wc * 64 + (lane & 15);

    if (MODE == 0) {
        #pragma unroll
        for (int mb = 0; mb < 4; mb++)
            #pragma unroll
            for (int nb = 0; nb < 4; nb++)
                #pragma unroll
                for (int r = 0; r < 4; r++)
                    out[(size_t)(rbase + mb * 16 + r) * ldo + cbase + nb * 16] = acc[mb][nb][r];
    } else {
        float* smS = (float*)lA;
        float* smQ = (float*)lB;
        __syncthreads();
        #pragma unroll
        for (int nb = 0; nb < 4; nb++) {
            float s = 0.f, q = 0.f;
            #pragma unroll
            for (int mb = 0; mb < 4; mb++)
                #pragma unroll
                for (int r = 0; r < 4; r++) {
                    float v = acc[mb][nb][r];
                    out[(size_t)(rbase + mb * 16 + r) * ldo + cbase + nb * 16] = v;
                    s += v; q += v * v;
                }
            s += __shfl_xor(s, 16, 64); s += __shfl_xor(s, 32, 64);
            q += __shfl_xor(q, 16, 64); q += __shfl_xor(q, 32, 64);
            if ((lane >> 4) == 0) {
                smS[wid * 64 + nb * 16 + lane] = s;
                smQ[wid * 64 + nb * 16 + lane] = q;
            }
        }
        __syncthreads();
        if (tid < 128) {
            int wcs = tid >> 6, c = tid & 63;
            float s = smS[wcs * 64 + c] + smS[(2 + wcs) * 64 + c];
            float q = smQ[wcs * 64 + c] + smQ[(2 + wcs) * 64 + c];
            int col = n0 + wcs * 64 + c;
            part[(size_t)col * 128 + yy] = s;
            part[131072 + (size_t)col * 128 + yy] = q;
        }
    }
}

// ---------------- gather neighbors, per-(p,o) max/min, per-channel stats ----
__global__ void gather_stats(const float* __restrict__ uv, const int* __restrict__ idx, int O,
                             float* __restrict__ ymax, float* __restrict__ ymin,
                             double* __restrict__ part, int ppb) {
    __shared__ double sd[256], sd2[256];
    int t = threadIdx.x;
    int R = 256 / O;
    int o = t % O;
    int q = t / O;
    double s = 0.0, s2 = 0.0;
    int p0 = blockIdx.x * ppb;
    int ld = 2 * O;
    for (int lp = q; lp < ppb; lp += R) {
        int p = p0 + lp;
        int b = p >> 10;
        const int* ir = idx + (size_t)p * KNN;
        float v = uv[(size_t)p * ld + O + o];
        float mx = -3.4e38f, mn = 3.4e38f;
        for (int kk = 0; kk < KNN; kk++) {
            int j = ir[kk];
            float u = uv[((size_t)((b << 10) + j)) * ld + o];
            float y = u + v;
            mx = fmaxf(mx, y); mn = fminf(mn, y);
            s += (double)y; s2 += (double)y * (double)y;
        }
        ymax[(size_t)p * O + o] = mx;
        ymin[(size_t)p * O + o] = mn;
    }
    sd[t] = s; sd2[t] = s2;
    __syncthreads();
    if (t < O) {
        double a = 0.0, a2 = 0.0;
        for (int qq = 0; qq < R; qq++) { a += sd[qq * O + t]; a2 += sd2[qq * O + t]; }
        part[(size_t)t * 1024 + blockIdx.x] = a;
        part[(size_t)(O + t) * 1024 + blockIdx.x] = a2;
    }
}

// ---------------- parallel finalize: one block per channel ------------------
__global__ void finalize_t(const double* __restrict__ part, int O,
                           const float* __restrict__ g, const float* __restrict__ bt,
                           float* __restrict__ scale, float* __restrict__ shift, double invCount) {
    __shared__ double sa[4], sb[4];
    int o = blockIdx.x;
    int t = threadIdx.x;
    int lane = t & 63, w = t >> 6;
    const double* ps = part + (size_t)o * 1024;
    const double* pq = part + (size_t)(O + o) * 1024;
    double s = 0.0, s2 = 0.0;
    #pragma unroll
    for (int b = 0; b < 4; b++) { s += ps[t + b * 256]; s2 += pq[t + b * 256]; }
    #pragma unroll
    for (int off = 32; off > 0; off >>= 1) { s += __shfl_xor(s, off, 64); s2 += __shfl_xor(s2, off, 64); }
    if (lane == 0) { sa[w] = s; sb[w] = s2; }
    __syncthreads();
    if (t == 0) {
        s = sa[0] + sa[1] + sa[2] + sa[3];
        s2 = sb[0] + sb[1] + sb[2] + sb[3];
        double mean = s * invCount;
        double var = s2 * invCount - mean * mean;
        if (var < 0.0) var = 0.0;
        float sc = (float)(1.0 / sqrt(var + 1e-5)) * g[o];
        scale[o] = sc;
        shift[o] = bt[o] - (float)mean * sc;
    }
}

// ---------------- parallel finalize for float partials (final conv) ---------
__global__ void finalize_f_t(const float* __restrict__ part,
                             const float* __restrict__ g, const float* __restrict__ bt,
                             float* __restrict__ scale, float* __restrict__ shift, double invCount) {
    __shared__ double sa[2], sb[2];
    int o = blockIdx.x;
    int t = threadIdx.x;   // 128 threads
    int lane = t & 63, w = t >> 6;
    double s  = (double)part[(size_t)o * 128 + t];
    double s2 = (double)part[131072 + (size_t)o * 128 + t];
    #pragma unroll
    for (int off = 32; off > 0; off >>= 1) { s += __shfl_xor(s, off, 64); s2 += __shfl_xor(s2, off, 64); }
    if (lane == 0) { sa[w] = s; sb[w] = s2; }
    __syncthreads();
    if (t == 0) {
        s = sa[0] + sa[1];
        s2 = sb[0] + sb[1];
        double mean = s * invCount;
        double var = s2 * invCount - mean * mean;
        if (var < 0.0) var = 0.0;
        float sc = (float)(1.0 / sqrt(var + 1e-5)) * g[o];
        scale[o] = sc;
        shift[o] = bt[o] - (float)mean * sc;
    }
}

// ---------------- edge conv epilogue: BN + leaky (max over k done) ----------
__global__ void apply_edge(const float* __restrict__ ymax, const float* __restrict__ ymin,
                           const float* __restrict__ scale, const float* __restrict__ shift,
                           float* __restrict__ xcat, int O, int off) {
    int i = blockIdx.x * 256 + threadIdx.x;
    if (i < P_ * O) {
        int p = i / O, o = i % O;
        float sc = scale[o];
        float y = (sc >= 0.f) ? ymax[i] : ymin[i];
        float val = y * sc + shift[o];
        xcat[(size_t)p * 512 + off + o] = LEAKY(val);
    }
}

// ---------------- pool partials: grid (16b, 16og, 4nz) = 1024 blocks --------
// R16: single-stage pool was latency-bound (1 block/CU, VALUBusy 5.9%, 72us).
// Partial pass: thread (o = og*64+(t&63), ch = t>>6) covers 64 n, unroll 4.
__global__ void pool_part(const float* __restrict__ h, const float* __restrict__ scale,
                          const float* __restrict__ shift,
                          float* __restrict__ pmax, double* __restrict__ psum) {
    __shared__ float smax[256];
    __shared__ double ssum[256];
    int b = blockIdx.x, og = blockIdx.y, nz = blockIdx.z;
    int t = threadIdx.x;
    int o = og * 64 + (t & 63);
    int ch = t >> 6;
    float sc = scale[o], sh = shift[o];
    float mx = -3.4e38f;
    double sm = 0.0;
    int n0 = nz * 256 + ch * 64;
    #pragma unroll 4
    for (int n = n0; n < n0 + 64; n++) {
        float y = h[((size_t)b * N_ + n) * 1024 + o] * sc + sh;
        y = LEAKY(y);
        mx = fmaxf(mx, y);
        sm += (double)y;
    }
    smax[t] = mx; ssum[t] = sm;
    __syncthreads();
    if (t < 64) {
        for (int c = 1; c < 4; c++) { mx = fmaxf(mx, smax[c * 64 + t]); sm += ssum[c * 64 + t]; }
        size_t pi = ((size_t)b * 4 + nz) * 1024 + o;
        pmax[pi] = mx;
        psum[pi] = sm;
    }
}

// ---------------- pool final: reduce 4 nz partials -> max / mean ------------
__global__ void pool_fin(const float* __restrict__ pmax, const double* __restrict__ psum,
                         float* __restrict__ pooled) {
    int b = blockIdx.x, og = blockIdx.y;
    int o = og * 256 + threadIdx.x;
    size_t base = (size_t)b * 4 * 1024 + o;
    float mx = pmax[base];
    double sm = psum[base];
    #pragma unroll
    for (int nz = 1; nz < 4; nz++) {
        mx = fmaxf(mx, pmax[base + nz * 1024]);
        sm += psum[base + nz * 1024];
    }
    pooled[(size_t)b * 2048 + o] = mx;
    pooled[(size_t)b * 2048 + 1024 + o] = (float)(sm * (1.0 / N_));
}

// ---------------- small FC: one wave per output -----------------------------
__global__ void fc_kernel(const float* __restrict__ in, int ldi,
                          const float* __restrict__ w, int ldw,
                          const float* __restrict__ bias,
                          float* __restrict__ out, int M, int Nn, int K) {
    int gw = (blockIdx.x * 256 + threadIdx.x) >> 6;
    int lane = threadIdx.x & 63;
    if (gw >= M * Nn) return;
    int m = gw / Nn, n = gw % Nn;
    const float* a = in + (size_t)m * ldi;
    const float* ww = w + (size_t)n * ldw;
    float s = 0.f;
    for (int kk = lane; kk < K; kk += 64) s += a[kk] * ww[kk];
    #pragma unroll
    for (int off = 32; off > 0; off >>= 1) s += __shfl_xor(s, off, 64);
    if (lane == 0) out[(size_t)m * Nn + n] = s + bias[n];
}

// ---------------- BN over batch axis (M=16) + leaky, in place ---------------
__global__ void bn_rows(float* __restrict__ z, int M, int O,
                        const float* __restrict__ g, const float* __restrict__ bt) {
    int o = blockIdx.x * 256 + threadIdx.x;
    if (o >= O) return;
    double s = 0.0, s2 = 0.0;
    for (int m = 0; m < M; m++) {
        float y = z[(size_t)m * O + o];
        s += (double)y; s2 += (double)y * (double)y;
    }
    double mean = s / M;
    double var = s2 / M - mean * mean;
    if (var < 0.0) var = 0.0;
    float sc = (float)(1.0 / sqrt(var + 1e-5)) * g[o];
    float sh = bt[o] - (float)mean * sc;
    for (int m = 0; m < M; m++) {
        float y = z[(size_t)m * O + o] * sc + sh;
        z[(size_t)m * O + o] = LEAKY(y);
    }
}

extern "C" void kernel_launch(void* const* d_in, const int* in_sizes, int n_in,
                              void* d_out, int out_size, void* d_ws, size_t ws_size,
                              hipStream_t stream) {
    const float* cloud = (const float*)d_in[0];
    const float* wf  = (const float*)d_in[17];
    const float* gf  = (const float*)d_in[19];
    const float* btf = (const float*)d_in[20];
    const float* wl1 = (const float*)d_in[21];
    const float* bl1 = (const float*)d_in[22];
    const float* gl1 = (const float*)d_in[23];
    const float* btl1= (const float*)d_in[24];
    const float* wl2 = (const float*)d_in[25];
    const float* bl2 = (const float*)d_in[26];
    const float* gl2 = (const float*)d_in[27];
    const float* btl2= (const float*)d_in[28];
    const float* wl3 = (const float*)d_in[29];
    const float* bl3 = (const float*)d_in[30];

    // workspace layout (bytes)
    const size_t OFF_XCAT  = 0;                        // 33554432
    const size_t OFF_UV    = 33554432;                 // 33554432 (A2 aliases UV+YMAX)
    const size_t OFF_YMAX  = 67108864;                 // 16777216 (xA alias: 12.6MB max)
    const size_t OFF_YMIN  = 83886080;                 // 16777216 (B2 alias)
    const size_t OFF_DIST  = 100663296;                // 67108864 (aliased as hraw)
    const size_t OFF_IDX   = 167772160;                // 1310720
    const size_t OFF_XX    = 169082880;                // 65536
    const size_t OFF_W2    = 169148416;                // 524288
    const size_t OFF_PART  = 169676800;                // 4194304: part doubles / partf / pool partials
    const size_t OFF_SCALE = 173871104;                // 4096
    const size_t OFF_SHIFT = 173875200;                // 4096
    const size_t OFF_POOL  = 173879296;                // 131072
    const size_t OFF_Z1    = 174010368;                // 32768
    const size_t OFF_Z2    = 174043136;                // 16384
    const size_t TOTAL     = 174059520;
    if (ws_size < TOTAL) return;

    char* ws = (char*)d_ws;
    float* xcat  = (float*)(ws + OFF_XCAT);
    float* uv    = (float*)(ws + OFF_UV);
    float* ymax  = (float*)(ws + OFF_YMAX);
    float* ymin  = (float*)(ws + OFF_YMIN);
    float* dist  = (float*)(ws + OFF_DIST);
    float* hraw  = (float*)(ws + OFF_DIST);
    ushort* A2   = (ushort*)(ws + OFF_UV);
    ushort* B2   = (ushort*)(ws + OFF_YMIN);
    ushort* xA   = (ushort*)(ws + OFF_YMAX);
    ushort* WB2  = (ushort*)(ws + OFF_PART);
    int*   idx   = (int*)  (ws + OFF_IDX);
    float* xx    = (float*)(ws + OFF_XX);
    float* W2    = (float*)(ws + OFF_W2);
    double* part = (double*)(ws + OFF_PART);
    float* partf = (float*)(ws + OFF_PART);
    float* ppmax = (float*)(ws + OFF_PART + 2097152);   // 16*4*1024 f = 256KB
    double* ppsum= (double*)(ws + OFF_PART + 2359296);  // 16*4*1024 d = 512KB (ends at +2871296 < 4MB)
    float* scale = (float*)(ws + OFF_SCALE);
    float* shift = (float*)(ws + OFF_SHIFT);
    float* pooled= (float*)(ws + OFF_POOL);
    float* z1    = (float*)(ws + OFF_Z1);
    float* z2    = (float*)(ws + OFF_Z2);

    const int Cs[4]   = {3, 64, 64, 128};
    const int Os[4]   = {64, 64, 128, 256};
    const int offs[4] = {0, 64, 128, 256};

    for (int L = 0; L < 4; L++) {
        int C = Cs[L], O = Os[L];
        const float* w  = (const float*)d_in[1 + 4 * L];
        const float* g  = (const float*)d_in[3 + 4 * L];
        const float* bt = (const float*)d_in[4 + 4 * L];
        const float* x  = (L == 0) ? cloud : (xcat + offs[L - 1]);
        int lda = (L == 0) ? 3 : 512;

        sqnorm<<<(P_ + 255) / 256, 256, 0, stream>>>(x, lda, C, xx);
        dist_kernel<<<dim3(136, 16), 256, 0, stream>>>(x, lda, C, xx, dist);
        topk_kernel<<<(P_ * 64) / 256, 256, 0, stream>>>(dist, idx);

        if (L == 0) {
            prep_w2<<<(2 * O * C + 255) / 256, 256, 0, stream>>>(w, W2, O, C);
            gemm_wt<<<dim3(2 * O / 64, P_ / 64), 256, 0, stream>>>(x, lda, W2, C, uv, 2 * O, C);
        } else {
            int K3 = 3 * C, nkt = K3 / 64;
            conv_split<<<(P_ * (C / 4) + 255) / 256, 256, 0, stream>>>(x, lda, C, P_, xA, 0);
            prep_w2_split<<<(2 * O * (C / 4) + 255) / 256, 256, 0, stream>>>(w, WB2, O, C);
            gemm_mfma<0><<<dim3(2 * O / 128, 128), 256, 0, stream>>>(xA, WB2, K3, nkt, uv, 2 * O, nullptr);
        }

        gather_stats<<<1024, 256, 0, stream>>>(uv, idx, O, ymax, ymin, part, 16);
        finalize_t<<<O, 256, 0, stream>>>(part, O, g, bt, scale, shift, 1.0 / ((double)P_ * KNN));
        apply_edge<<<(P_ * O + 255) / 256, 256, 0, stream>>>(ymax, ymin, scale, shift, xcat, O, offs[L]);
    }

    // final 1x1 conv via split-bf16 MFMA GEMM with fused (transposed) col stats
    conv_split<<<(P_ * 128 + 255) / 256, 256, 0, stream>>>(xcat, 512, 512, P_, A2, 0);
    conv_split<<<(1024 * 128 + 255) / 256, 256, 0, stream>>>(wf, 512, 512, 1024, B2, 1);
    gemm_mfma<2><<<dim3(8, 128), 256, 0, stream>>>(A2, B2, 1536, 24, hraw, 1024, partf);

    finalize_f_t<<<1024, 128, 0, stream>>>(partf, gf, btf, scale, shift, 1.0 / (double)P_);
    pool_part<<<dim3(16, 16, 4), 256, 0, stream>>>(hraw, scale, shift, ppmax, ppsum);
    pool_fin<<<dim3(16, 4), 256, 0, stream>>>(ppmax, ppsum, pooled);

    // MLP head
    fc_kernel<<<(16 * 512 * 64) / 256, 256, 0, stream>>>(pooled, 2048, wl1, 2048, bl1, z1, 16, 512, 2048);
    bn_rows<<<2, 256, 0, stream>>>(z1, 16, 512, gl1, btl1);
    fc_kernel<<<(16 * 256 * 64) / 256, 256, 0, stream>>>(z1, 512, wl2, 512, bl2, z2, 16, 256, 512);
    bn_rows<<<1, 256, 0, stream>>>(z2, 16, 256, gl2, btl2);
    fc_kernel<<<(16 * 40 * 64 + 255) / 256, 256, 0, stream>>>(z2, 256, wl3, 256, bl3, (float*)d_out, 16, 40, 256);
}